// Round 2
// baseline (1272.782 us; speedup 1.0000x reference)
//
#include <hip/hip_runtime.h>
#include <math.h>

namespace {
constexpr int BB = 32;
constexpr int NN = 1024;
constexpr int ET = 16;
constexpr int HH = 64;
constexpr int CIN = 65;       // Din + HID
constexpr int KI = 2*CIN;     // 130
constexpr int COG = 2*HH;     // 128
constexpr int COU = HH;       // 64
constexpr int PP = 288;
constexpr int FF = 7;
constexpr int FRQ = 12;

__device__ __forceinline__ float dot16v(float4 a0, float4 a1, float4 a2, float4 a3,
                                        float4 b0, float4 b1, float4 b2, float4 b3) {
    return a0.x*b0.x + a0.y*b0.y + a0.z*b0.z + a0.w*b0.w
         + a1.x*b1.x + a1.y*b1.y + a1.z*b1.z + a1.w*b1.w
         + a2.x*b2.x + a2.y*b2.y + a2.z*b2.z + a2.w*b2.w
         + a3.x*b3.x + a3.y*b3.y + a3.z*b3.z + a3.w*b3.w;
}

// se[N][16] = SE@W_se + b_se ; tt[B][16] = T_tod[..] + T_dow[..]
__global__ void k_prep1(const float* __restrict__ SE, const float* __restrict__ Wse,
                        const float* __restrict__ bse, const float* __restrict__ Ttod,
                        const float* __restrict__ Tdow, const int* __restrict__ tidx,
                        float* __restrict__ se, float* __restrict__ tt) {
    int idx = blockIdx.x*blockDim.x + threadIdx.x;
    if (idx < NN*ET) {
        int n = idx / ET, d = idx % ET;
        float acc = bse[d];
        #pragma unroll
        for (int e = 0; e < ET; ++e) acc += SE[n*ET + e]*Wse[e*ET + d];
        se[idx] = acc;
    } else if (idx < NN*ET + BB*ET) {
        int r = idx - NN*ET;
        int b = r / ET, d = r % ET;
        int t = tidx[b]*FRQ;
        tt[r] = Ttod[(t % PP)*ET + d] + Tdow[((t/PP) % FF)*ET + d];
    }
}

__global__ void k_prep2(const float* __restrict__ se, const float* __restrict__ tt,
                        float* __restrict__ ste) {
    int idx = blockIdx.x*blockDim.x + threadIdx.x;
    if (idx >= BB*NN*ET) return;
    int d = idx % ET;
    int n = (idx/ET) % NN;
    int b = idx/(ET*NN);
    ste[idx] = se[n*ET+d] + tt[b*ET+d];
}

// W_batch = tt[b] . Wpool  for gate and upd pools
__global__ void k_prep3(const float* __restrict__ tt, const float* __restrict__ Wg,
                        const float* __restrict__ Wu, float* __restrict__ Wbg,
                        float* __restrict__ Wbu) {
    int idx = blockIdx.x*blockDim.x + threadIdx.x;
    constexpr int NG = BB*KI*COG;
    constexpr int NU2 = BB*KI*COU;
    if (idx < NG) {
        int b = idx/(KI*COG), rem = idx%(KI*COG);
        float acc = 0.f;
        #pragma unroll
        for (int d = 0; d < ET; ++d) acc += tt[b*ET+d]*Wg[d*(KI*COG) + rem];
        Wbg[idx] = acc;
    } else if (idx < NG + NU2) {
        int j = idx - NG;
        int b = j/(KI*COU), rem = j%(KI*COU);
        float acc = 0.f;
        #pragma unroll
        for (int d = 0; d < ET; ++d) acc += tt[b*ET+d]*Wu[d*(KI*COU) + rem];
        Wbu[j] = acc;   // FIXED: was Wbu[idx] (offset by NG -> Wbu never written)
    }
}

// softmax row stats (M, 1/L) + normalized x-channel of A@ins (shared by both passes)
__global__ __launch_bounds__(256) void k_stats(
    const float* __restrict__ ste, const float* __restrict__ R,
    const float* __restrict__ SC, const float* __restrict__ x,
    float* __restrict__ Mrow, float* __restrict__ Linv, float* __restrict__ axx)
{
    int b = blockIdx.y, t = threadIdx.x;
    int w = t >> 6, lane = t & 63;
    int rbase = blockIdx.x*64 + w*16;
    const float* steb = ste + (size_t)b*NN*ET;
    float mx[16], ls[16], xa[16];
    #pragma unroll
    for (int r = 0; r < 16; ++r) { mx[r] = -INFINITY; ls[r] = 0.f; xa[r] = 0.f; }
    for (int j = 0; j < 16; ++j) {
        int m = j*64 + lane;
        const float4* cp = (const float4*)(steb + m*ET);
        float4 c0 = cp[0], c1 = cp[1], c2 = cp[2], c3 = cp[3];
        float xv = x[(size_t)b*NN + m];
        const float* Rrow = R + ((size_t)b*NN + rbase)*NN + m;
        const float* SCrow = SC + (size_t)rbase*NN + m;
        #pragma unroll
        for (int r = 0; r < 16; ++r) {
            const float4* rp = (const float4*)(steb + (rbase + r)*ET);
            float s = dot16v(rp[0],rp[1],rp[2],rp[3],c0,c1,c2,c3);
            s = fmaxf(s, 0.f) + Rrow[(size_t)r*NN] + SCrow[(size_t)r*NN];
            float nm = fmaxf(mx[r], s);
            float e0 = __expf(mx[r] - nm);
            float e1 = __expf(s - nm);
            ls[r] = ls[r]*e0 + e1;
            xa[r] = xa[r]*e0 + e1*xv;
            mx[r] = nm;
        }
    }
    #pragma unroll
    for (int r = 0; r < 16; ++r) {
        float M = mx[r];
        #pragma unroll
        for (int o = 32; o > 0; o >>= 1) M = fmaxf(M, __shfl_xor(M, o));
        float scl = __expf(mx[r] - M);
        float l = ls[r]*scl, xs = xa[r]*scl;
        #pragma unroll
        for (int o = 32; o > 0; o >>= 1) { l += __shfl_xor(l, o); xs += __shfl_xor(xs, o); }
        if (lane == 0) {
            size_t row = (size_t)b*NN + rbase + r;
            Mrow[row] = M;
            Linv[row] = 1.f/l;
            axx[row] = xs/l;
        }
    }
}

// out[b, rows, 0:64] = softmax(scores) @ V   (P recomputed from precomputed M, scaled by 1/L)
__global__ __launch_bounds__(256) void k_pv(
    const float* __restrict__ ste, const float* __restrict__ R,
    const float* __restrict__ SC, const float* __restrict__ V,
    const float* __restrict__ Mrow, const float* __restrict__ Linv,
    float* __restrict__ out)
{
    __shared__ float V_l[64][64];
    __shared__ float P_l[64][65];   // stride 65: conflict-free writes & reads
    int b = blockIdx.y, t = threadIdx.x;
    int w = t >> 6, lane = t & 63;
    int rbase = blockIdx.x*64;
    const float* steb = ste + (size_t)b*NN*ET;
    int rsub = lane >> 3, cgrp = lane & 7;
    float acc[2][8];
    #pragma unroll
    for (int q = 0; q < 2; ++q)
        #pragma unroll
        for (int c = 0; c < 8; ++c) acc[q][c] = 0.f;
    for (int j = 0; j < 16; ++j) {
        {   // stage V tile [64 m][64 ch]
            const float4* Vg = (const float4*)(V + ((size_t)b*NN + (size_t)j*64)*HH);
            float4* Vl = (float4*)&V_l[0][0];
            Vl[t] = Vg[t];
            Vl[t+256] = Vg[t+256];
            Vl[t+512] = Vg[t+512];
            Vl[t+768] = Vg[t+768];
        }
        {   // phase1: wave w computes P rows [16w..16w+15], col = lane
            int m = j*64 + lane;
            const float4* cp = (const float4*)(steb + m*ET);
            float4 c0 = cp[0], c1 = cp[1], c2 = cp[2], c3 = cp[3];
            #pragma unroll
            for (int r = 0; r < 16; ++r) {
                int rr = w*16 + r;
                int row = rbase + rr;
                const float4* rp = (const float4*)(steb + row*ET);
                float s = dot16v(rp[0],rp[1],rp[2],rp[3],c0,c1,c2,c3);
                s = fmaxf(s, 0.f) + R[((size_t)b*NN + row)*NN + m] + SC[(size_t)row*NN + m];
                P_l[rr][lane] = __expf(s - Mrow[(size_t)b*NN + row]);
            }
        }
        __syncthreads();
        {   // phase2: register-blocked P@V, 2 rows x 8 ch per lane
            int r0i = w*16 + rsub*2, r1i = r0i + 1;
            #pragma unroll 8
            for (int m = 0; m < 64; ++m) {
                float a0 = P_l[r0i][m], a1 = P_l[r1i][m];
                const float4* vp = (const float4*)&V_l[m][cgrp*8];
                float4 v0 = vp[0], v1 = vp[1];
                acc[0][0] += a0*v0.x; acc[0][1] += a0*v0.y;
                acc[0][2] += a0*v0.z; acc[0][3] += a0*v0.w;
                acc[0][4] += a0*v1.x; acc[0][5] += a0*v1.y;
                acc[0][6] += a0*v1.z; acc[0][7] += a0*v1.w;
                acc[1][0] += a1*v0.x; acc[1][1] += a1*v0.y;
                acc[1][2] += a1*v0.z; acc[1][3] += a1*v0.w;
                acc[1][4] += a1*v1.x; acc[1][5] += a1*v1.y;
                acc[1][6] += a1*v1.z; acc[1][7] += a1*v1.w;
            }
        }
        __syncthreads();
    }
    int r0i = w*16 + rsub*2;
    #pragma unroll
    for (int q = 0; q < 2; ++q) {
        int row = rbase + r0i + q;
        float li = Linv[(size_t)b*NN + row];
        float* op = out + ((size_t)b*NN + row)*HH + cgrp*8;
        float4 o0 = make_float4(acc[q][0]*li, acc[q][1]*li, acc[q][2]*li, acc[q][3]*li);
        float4 o1 = make_float4(acc[q][4]*li, acc[q][5]*li, acc[q][6]*li, acc[q][7]*li);
        ((float4*)op)[0] = o0;
        ((float4*)op)[1] = o1;
    }
}

// partial[b,n,o] = sum_ki x_g[b,n,ki]*W_batch[b,ki,o] + tt-part of bias
template<int COUT>
__global__ __launch_bounds__(256) void k_bapply(
    const float* __restrict__ Wb, const float* __restrict__ bias,
    const float* __restrict__ tt, const float* __restrict__ x,
    const float* __restrict__ sv, const float* __restrict__ axx,
    const float* __restrict__ axs, float* __restrict__ partial)
{
    constexpr int NPER = 256/COUT;
    __shared__ float Wb_l[KI*COUT];
    __shared__ float xg_l[NPER][KI];
    int b = blockIdx.y, t = threadIdx.x;
    int ntile = blockIdx.x;
    for (int e = t; e < KI*COUT; e += 256) Wb_l[e] = Wb[(size_t)b*KI*COUT + e];
    int o = t % COUT, nsub = t / COUT;
    float bo = 0.f;
    #pragma unroll
    for (int d = 0; d < ET; ++d) bo += tt[b*ET+d]*bias[d*COUT+o];
    for (int it = 0; it < 64/NPER; ++it) {
        int n0 = ntile*64 + it*NPER;
        __syncthreads();
        for (int e = t; e < NPER*KI; e += 256) {
            int nn = e / KI, ki = e % KI;
            size_t nb = (size_t)b*NN + n0 + nn;
            float v;
            if (ki == 0) v = x[nb];
            else if (ki < CIN) v = sv[nb*HH + ki - 1];
            else if (ki == CIN) v = axx[nb];
            else v = axs[nb*HH + ki - CIN - 1];
            xg_l[nn][ki] = v;
        }
        __syncthreads();
        float acc = bo;
        #pragma unroll 13
        for (int ki = 0; ki < KI; ++ki) acc += xg_l[nsub][ki]*Wb_l[ki*COUT + o];
        partial[((size_t)b*NN + n0 + nsub)*COUT + o] = acc;
    }
}

// gate: add node part (W_node built in LDS from se[n].W_gate), sigmoid, write zs=z*state and r
__global__ __launch_bounds__(256) void k_napply_gate(
    const float* __restrict__ se_g, const float* __restrict__ Wg,
    const float* __restrict__ bias,
    const float* __restrict__ x, const float* __restrict__ state,
    const float* __restrict__ axx, const float* __restrict__ axs,
    const float* __restrict__ partial,
    float* __restrict__ zs, float* __restrict__ rout)
{
    __shared__ float Wn[KI*COG];     // 66.5 KB
    __shared__ float xg_l[8][KI];
    __shared__ float se_l[ET];
    int n = blockIdx.x, t = threadIdx.x;
    if (t < ET) se_l[t] = se_g[n*ET + t];
    __syncthreads();
    for (int e = t; e < KI*COG; e += 256) {
        float acc = 0.f;
        #pragma unroll
        for (int d = 0; d < ET; ++d) acc += se_l[d]*Wg[d*(KI*COG) + e];
        Wn[e] = acc;
    }
    int o = t & (COG-1), bh = t >> 7;
    float bo = 0.f;
    #pragma unroll
    for (int d = 0; d < ET; ++d) bo += se_l[d]*bias[d*COG + o];
    for (int chunk = 0; chunk < 4; ++chunk) {
        __syncthreads();
        for (int e = t; e < 8*KI; e += 256) {
            int bl = e / KI, ki = e % KI;
            size_t nb = (size_t)(chunk*8 + bl)*NN + n;
            float v;
            if (ki == 0) v = x[nb];
            else if (ki < CIN) v = state[nb*HH + ki - 1];
            else if (ki == CIN) v = axx[nb];
            else v = axs[nb*HH + ki - CIN - 1];
            xg_l[bl][ki] = v;
        }
        __syncthreads();
        #pragma unroll
        for (int bq = 0; bq < 4; ++bq) {
            int bl = bq*2 + bh;
            int bb = chunk*8 + bl;
            float acc = bo + partial[((size_t)bb*NN + n)*COG + o];
            #pragma unroll 13
            for (int ki = 0; ki < KI; ++ki) acc += xg_l[bl][ki]*Wn[ki*COG + o];
            float g = 1.f/(1.f + __expf(-acc));
            size_t base = ((size_t)bb*NN + n)*HH;
            if (o < HH) zs[base + o] = g * state[base + o];
            else rout[base + o - HH] = g;
        }
    }
}

// upd: add node part, tanh, final out = r*state + (1-r)*hc
__global__ __launch_bounds__(256) void k_napply_upd(
    const float* __restrict__ se_g, const float* __restrict__ Wu,
    const float* __restrict__ bias,
    const float* __restrict__ x, const float* __restrict__ zs,
    const float* __restrict__ axx, const float* __restrict__ axs,
    const float* __restrict__ partial, const float* __restrict__ rin,
    const float* __restrict__ state, float* __restrict__ out)
{
    __shared__ float Wn[KI*COU];     // 33 KB
    __shared__ float xg_l[8][KI];
    __shared__ float se_l[ET];
    int n = blockIdx.x, t = threadIdx.x;
    if (t < ET) se_l[t] = se_g[n*ET + t];
    __syncthreads();
    for (int e = t; e < KI*COU; e += 256) {
        float acc = 0.f;
        #pragma unroll
        for (int d = 0; d < ET; ++d) acc += se_l[d]*Wu[d*(KI*COU) + e];
        Wn[e] = acc;
    }
    int o = t & (COU-1), bq4 = t >> 6;
    float bo = 0.f;
    #pragma unroll
    for (int d = 0; d < ET; ++d) bo += se_l[d]*bias[d*COU + o];
    for (int chunk = 0; chunk < 4; ++chunk) {
        __syncthreads();
        for (int e = t; e < 8*KI; e += 256) {
            int bl = e / KI, ki = e % KI;
            size_t nb = (size_t)(chunk*8 + bl)*NN + n;
            float v;
            if (ki == 0) v = x[nb];
            else if (ki < CIN) v = zs[nb*HH + ki - 1];
            else if (ki == CIN) v = axx[nb];
            else v = axs[nb*HH + ki - CIN - 1];
            xg_l[bl][ki] = v;
        }
        __syncthreads();
        #pragma unroll
        for (int bq = 0; bq < 2; ++bq) {
            int bl = bq*4 + bq4;
            int bb = chunk*8 + bl;
            float acc = bo + partial[((size_t)bb*NN + n)*COU + o];
            #pragma unroll 13
            for (int ki = 0; ki < KI; ++ki) acc += xg_l[bl][ki]*Wn[ki*COU + o];
            float hc = tanhf(acc);
            size_t base = ((size_t)bb*NN + n)*HH;
            float rv = rin[base + o];
            out[base + o] = rv*state[base + o] + (1.f - rv)*hc;
        }
    }
}

} // namespace

extern "C" void kernel_launch(void* const* d_in, const int* in_sizes, int n_in,
                              void* d_out, int out_size, void* d_ws, size_t ws_size,
                              hipStream_t stream) {
    const float* x     = (const float*)d_in[0];
    const float* R     = (const float*)d_in[1];
    const float* state = (const float*)d_in[2];
    const float* SC    = (const float*)d_in[3];
    const float* SE    = (const float*)d_in[4];
    const float* W_se  = (const float*)d_in[5];
    const float* b_se  = (const float*)d_in[6];
    const float* T_tod = (const float*)d_in[7];
    const float* T_dow = (const float*)d_in[8];
    const float* W_g   = (const float*)d_in[9];
    const float* b_g   = (const float*)d_in[10];
    const float* W_u   = (const float*)d_in[11];
    const float* b_u   = (const float*)d_in[12];
    const int*   tidx  = (const int*)d_in[13];
    float* out = (float*)d_out;
    float* ws = (float*)d_ws;

    float* se   = ws;                 // 16384
    float* tt   = se   + 16384;       // 512
    float* ste  = tt   + 512;         // 524288
    float* Wbg  = ste  + 524288;      // 532480
    float* Wbu  = Wbg  + 532480;      // 266240
    float* Mr   = Wbu  + 266240;      // 32768
    float* Li   = Mr   + 32768;       // 32768
    float* axx  = Li   + 32768;       // 32768
    float* axgs = axx  + 32768;       // 2097152
    float* axcs = axgs + 2097152;     // 2097152
    float* zs   = axcs + 2097152;     // 2097152
    float* rr   = zs   + 2097152;     // 2097152
    float* pg   = rr   + 2097152;     // 4194304
    float* pu   = pg   + 4194304;     // 2097152  (total ~64.5 MB)

    k_prep1<<<66, 256, 0, stream>>>(SE, W_se, b_se, T_tod, T_dow, tidx, se, tt);
    k_prep2<<<2048, 256, 0, stream>>>(se, tt, ste);
    k_prep3<<<3120, 256, 0, stream>>>(tt, W_g, W_u, Wbg, Wbu);
    k_stats<<<dim3(16,32), 256, 0, stream>>>(ste, R, SC, x, Mr, Li, axx);
    k_pv<<<dim3(16,32), 256, 0, stream>>>(ste, R, SC, state, Mr, Li, axgs);
    k_bapply<COG><<<dim3(16,32), 256, 0, stream>>>(Wbg, b_g, tt, x, state, axx, axgs, pg);
    k_napply_gate<<<1024, 256, 0, stream>>>(se, W_g, b_g, x, state, axx, axgs, pg, zs, rr);
    k_pv<<<dim3(16,32), 256, 0, stream>>>(ste, R, SC, zs, Mr, Li, axcs);
    k_bapply<COU><<<dim3(16,32), 256, 0, stream>>>(Wbu, b_u, tt, x, zs, axx, axcs, pu);
    k_napply_upd<<<1024, 256, 0, stream>>>(se, W_u, b_u, x, zs, axx, axcs, pu, rr, state, out);
}

// Round 5
// 506.455 us; speedup vs baseline: 2.5131x; 2.5131x over previous
//
#include <hip/hip_runtime.h>
#include <math.h>

namespace {
constexpr int BB = 32;
constexpr int NN = 1024;
constexpr int ET = 16;
constexpr int HH = 64;
constexpr int CIN = 65;       // Din + HID
constexpr int KI = 2*CIN;     // 130
constexpr int COG = 2*HH;     // 128
constexpr int COU = HH;       // 64
constexpr int PP = 288;
constexpr int FF = 7;
constexpr int FRQ = 12;

typedef __attribute__((ext_vector_type(4))) float f32x4;
typedef __attribute__((ext_vector_type(8))) short s16x8;
typedef unsigned long long ull;

__device__ __forceinline__ float bf2f(unsigned short u) {
    unsigned v = ((unsigned)u) << 16;
    return __builtin_bit_cast(float, v);
}
__device__ __forceinline__ unsigned short f2bf(float f) {
    unsigned u = __builtin_bit_cast(unsigned, f);
    u += 0x7fffu + ((u >> 16) & 1u);   // RNE
    return (unsigned short)(u >> 16);
}

// ---------------- prep kernels ----------------
__global__ void k_prep1(const float* __restrict__ SE, const float* __restrict__ Wse,
                        const float* __restrict__ bse, const float* __restrict__ Ttod,
                        const float* __restrict__ Tdow, const int* __restrict__ tidx,
                        float* __restrict__ se, float* __restrict__ tt) {
    int idx = blockIdx.x*blockDim.x + threadIdx.x;
    if (idx < NN*ET) {
        int n = idx / ET, d = idx % ET;
        float acc = bse[d];
        #pragma unroll
        for (int e = 0; e < ET; ++e) acc += SE[n*ET + e]*Wse[e*ET + d];
        se[idx] = acc;
    } else if (idx < NN*ET + BB*ET) {
        int r = idx - NN*ET;
        int b = r / ET, d = r % ET;
        int t = tidx[b]*FRQ;
        tt[r] = Ttod[(t % PP)*ET + d] + Tdow[((t/PP) % FF)*ET + d];
    }
}

// ste_bf[b][n][d] = bf16(se[n][d] + tt[b][d])
__global__ void k_prep2bf(const float* __restrict__ se, const float* __restrict__ tt,
                          unsigned short* __restrict__ stebf) {
    int idx = blockIdx.x*blockDim.x + threadIdx.x;
    if (idx >= BB*NN*ET) return;
    int d = idx % ET;
    int n = (idx/ET) % NN;
    int b = idx/(ET*NN);
    stebf[idx] = f2bf(se[n*ET+d] + tt[b*ET+d]);
}

__global__ void k_prep3(const float* __restrict__ tt, const float* __restrict__ Wg,
                        const float* __restrict__ Wu, float* __restrict__ Wbg,
                        float* __restrict__ Wbu) {
    int idx = blockIdx.x*blockDim.x + threadIdx.x;
    constexpr int NG = BB*KI*COG;
    constexpr int NU2 = BB*KI*COU;
    if (idx < NG) {
        int b = idx/(KI*COG), rem = idx%(KI*COG);
        float acc = 0.f;
        #pragma unroll
        for (int d = 0; d < ET; ++d) acc += tt[b*ET+d]*Wg[d*(KI*COG) + rem];
        Wbg[idx] = acc;
    } else if (idx < NG + NU2) {
        int j = idx - NG;
        int b = j/(KI*COU), rem = j%(KI*COU);
        float acc = 0.f;
        #pragma unroll
        for (int d = 0; d < ET; ++d) acc += tt[b*ET+d]*Wu[d*(KI*COU) + rem];
        Wbu[j] = acc;
    }
}

// ---------------- fused attention pass ----------------
// S strip: 16 rows x 1024 cols bf16, padded row stride 1040 (16B-aligned rows,
// 4-way max banks). Vt: V-tile transposed [64 ch][72 stride] bf16.
constexpr int SSTR   = 1040;       // bf16 elements per S row
constexpr int S_OFF  = 0;          // 16*1040*2 = 33280
constexpr int V_OFF  = 33280;      // 64*72*2   = 9216
constexpr int VSTR   = 72;
constexpr int XV_OFF = 42496;      // 1024 f32  = 4096
constexpr int MSH_OFF  = 46592;    // 256
constexpr int MSHC_OFF = 46848;    // 64
constexpr int LP_OFF   = 46912;    // 256
constexpr int AXP_OFF  = 47168;    // 256
constexpr int LSH_OFF  = 47424;    // 64
constexpr int SMEM_BYTES = 47488;

template<int PASS>
__global__ __launch_bounds__(256, 3) void k_attn(
    const unsigned short* __restrict__ stebf, const float* __restrict__ Rg,
    const float* __restrict__ SCg, const float* __restrict__ xg,
    const float* __restrict__ Vglob,     // f32 V source (state / z*state)
    float* __restrict__ Mr, float* __restrict__ Li, float* __restrict__ Axx,
    float* __restrict__ outp)
{
    extern __shared__ char smem[];
    const int t = threadIdx.x, lane = t & 63, w = t >> 6;
    const int c15 = lane & 15, g = lane >> 4;
    const int strip = blockIdx.x, b = blockIdx.y;
    const size_t bN = (size_t)b * NN;
    const int r0 = strip * 16;

    float* Mshf  = (float*)(smem + MSH_OFF);
    float* MshCf = (float*)(smem + MSHC_OFF);
    float* Lpf   = (float*)(smem + LP_OFF);
    float* Axpf  = (float*)(smem + AXP_OFF);
    float* Lshf  = (float*)(smem + LSH_OFF);

    if (PASS == 1) {   // stage x[b] into LDS
        ((float4*)(smem + XV_OFF))[t] = ((const float4*)(xg + bN))[t];
    }

    // ---- phase a: scores via MFMA; wave w owns cols w*16+c15 (+j*64) ----
    {
        s16x8 af = {0,0,0,0,0,0,0,0};
        if (g < 2) af = *(const s16x8*)(stebf + (bN + r0 + c15)*ET + g*8);
        const float* Rb  = Rg  + (bN + r0 + g*4)*NN;
        const float* SCb = SCg + (size_t)(r0 + g*4)*NN;
        float mx0 = -INFINITY, mx1 = -INFINITY, mx2 = -INFINITY, mx3 = -INFINITY;
        float rc[4], scv[4];
        {
            int col = w*16 + c15;
            #pragma unroll
            for (int q = 0; q < 4; ++q) { rc[q] = Rb[(size_t)q*NN + col]; scv[q] = SCb[(size_t)q*NN + col]; }
        }
        for (int j = 0; j < 16; ++j) {
            int colB = j*64 + w*16 + c15;
            s16x8 bf = {0,0,0,0,0,0,0,0};
            if (g < 2) bf = *(const s16x8*)(stebf + (bN + colB)*ET + g*8);
            float rn[4] = {0.f,0.f,0.f,0.f}, sn[4] = {0.f,0.f,0.f,0.f};
            if (j < 15) {
                int col = colB + 64;
                #pragma unroll
                for (int q = 0; q < 4; ++q) { rn[q] = Rb[(size_t)q*NN + col]; sn[q] = SCb[(size_t)q*NN + col]; }
            }
            f32x4 zero = {0.f,0.f,0.f,0.f};
            f32x4 d = __builtin_amdgcn_mfma_f32_16x16x32_bf16(af, bf, zero, 0, 0, 0);
            #pragma unroll
            for (int q = 0; q < 4; ++q) {
                float s = fmaxf(d[q], 0.f) + rc[q] + scv[q];
                if (PASS == 1) {
                    if (q == 0) mx0 = fmaxf(mx0, s);
                    if (q == 1) mx1 = fmaxf(mx1, s);
                    if (q == 2) mx2 = fmaxf(mx2, s);
                    if (q == 3) mx3 = fmaxf(mx3, s);
                }
                int rowl = g*4 + q;
                *(unsigned short*)(smem + S_OFF + (unsigned)(rowl*SSTR + colB)*2u) = f2bf(s);
            }
            #pragma unroll
            for (int q = 0; q < 4; ++q) { rc[q] = rn[q]; scv[q] = sn[q]; }
        }
        if (PASS == 1) {
            float mxa[4] = {mx0, mx1, mx2, mx3};
            #pragma unroll
            for (int q = 0; q < 4; ++q) {
                float m = mxa[q];
                m = fmaxf(m, __shfl_xor(m, 1));
                m = fmaxf(m, __shfl_xor(m, 2));
                m = fmaxf(m, __shfl_xor(m, 4));
                m = fmaxf(m, __shfl_xor(m, 8));
                if (c15 == 0) Mshf[w*16 + g*4 + q] = m;
            }
        }
    }
    __syncthreads();

    if (PASS == 1) {
        if (t < 16) {
            float m = fmaxf(fmaxf(Mshf[t], Mshf[16+t]), fmaxf(Mshf[32+t], Mshf[48+t]));
            MshCf[t] = m;
            Mr[bN + r0 + t] = m;
        }
    } else {
        if (t < 16) MshCf[t] = Mr[bN + r0 + t];
        if (t >= 64 && t < 80) Lshf[t-64] = Li[bN + r0 + (t-64)];
    }
    __syncthreads();

    // ---- phase b: sweep (exp in place; PASS1 also L and axx) ----
    {
        const int rowl = c15;
        const float m = MshCf[rowl];
        float L = 0.f, ax = 0.f;
        for (int it = 0; it < 16; ++it) {
            int k = w*256 + it*16 + g*4;
            unsigned byteo = (unsigned)(rowl*SSTR + k)*2u;
            ull v = *(ull*)(smem + S_OFF + byteo);
            float s0 = bf2f((unsigned short)v);
            float s1 = bf2f((unsigned short)(v >> 16));
            float s2 = bf2f((unsigned short)(v >> 32));
            float s3 = bf2f((unsigned short)(v >> 48));
            float p0 = __expf(s0 - m), p1 = __expf(s1 - m);
            float p2 = __expf(s2 - m), p3 = __expf(s3 - m);
            if (PASS == 1) {
                float4 xq = *(const float4*)(smem + XV_OFF + k*4);
                L += (p0 + p1) + (p2 + p3);
                ax += p0*xq.x + p1*xq.y + p2*xq.z + p3*xq.w;
            }
            unsigned lo = ((unsigned)f2bf(p1) << 16) | f2bf(p0);
            unsigned hi = ((unsigned)f2bf(p3) << 16) | f2bf(p2);
            *(ull*)(smem + S_OFF + byteo) = ((ull)hi << 32) | lo;
        }
        if (PASS == 1) {
            L += __shfl_xor(L, 16); L += __shfl_xor(L, 32);
            ax += __shfl_xor(ax, 16); ax += __shfl_xor(ax, 32);
            if (g == 0) { Lpf[w*16 + rowl] = L; Axpf[w*16 + rowl] = ax; }
        }
    }
    __syncthreads();
    if (PASS == 1) {
        if (t < 16) {
            float Lt = Lpf[t] + Lpf[16+t] + Lpf[32+t] + Lpf[48+t];
            float li = 1.f / Lt;
            Lshf[t] = li;
            Li[bN + r0 + t] = li;
            Axx[bN + r0 + t] = (Axpf[t] + Axpf[16+t] + Axpf[32+t] + Axpf[48+t]) * li;
        }
        __syncthreads();
    }

    // ---- phase c: PV via MFMA; wave w owns out cols [w*16, w*16+16) ----
    // A = P rows (contiguous s16x8 from S), B = Vt[ch][m] (contiguous s16x8).
    {
        f32x4 acc = {0.f,0.f,0.f,0.f};
        const float* Vsrc = Vglob + bN*HH;
        const int chS = t & 63, q4 = t >> 6;
        for (int j = 0; j < 16; ++j) {
            #pragma unroll
            for (int itq = 0; itq < 4; ++itq) {
                int mm0 = itq*16 + q4*4;
                const float* vp = Vsrc + (size_t)(j*64 + mm0)*HH + chS;
                float v0 = vp[0], v1 = vp[HH], v2 = vp[2*HH], v3 = vp[3*HH];
                ull o = (ull)f2bf(v0) | ((ull)f2bf(v1)<<16)
                      | ((ull)f2bf(v2)<<32) | ((ull)f2bf(v3)<<48);
                *(ull*)(smem + V_OFF + (unsigned)(chS*VSTR + mm0)*2u) = o;
            }
            __syncthreads();
            #pragma unroll
            for (int ks = 0; ks < 2; ++ks) {
                s16x8 a  = *(const s16x8*)(smem + S_OFF + (unsigned)(c15*SSTR + j*64 + ks*32 + g*8)*2u);
                s16x8 bv = *(const s16x8*)(smem + V_OFF + (unsigned)((w*16 + c15)*VSTR + ks*32 + g*8)*2u);
                acc = __builtin_amdgcn_mfma_f32_16x16x32_bf16(a, bv, acc, 0, 0, 0);
            }
            __syncthreads();
        }
        #pragma unroll
        for (int q = 0; q < 4; ++q) {
            int rowl = g*4 + q;
            float li = Lshf[rowl];
            outp[(bN + r0 + rowl)*HH + w*16 + c15] = acc[q] * li;
        }
    }
}

// ---------------- apply kernels ----------------
template<int COUT>
__global__ __launch_bounds__(256) void k_bapply(
    const float* __restrict__ Wb, const float* __restrict__ bias,
    const float* __restrict__ tt, const float* __restrict__ x,
    const float* __restrict__ sv, const float* __restrict__ axx,
    const float* __restrict__ axs, float* __restrict__ partial)
{
    constexpr int NPER = 256/COUT;
    __shared__ float Wb_l[KI*COUT];
    __shared__ float xg_l[NPER][KI];
    int b = blockIdx.y, t = threadIdx.x;
    int ntile = blockIdx.x;
    for (int e = t; e < KI*COUT; e += 256) Wb_l[e] = Wb[(size_t)b*KI*COUT + e];
    int o = t % COUT, nsub = t / COUT;
    float bo = 0.f;
    #pragma unroll
    for (int d = 0; d < ET; ++d) bo += tt[b*ET+d]*bias[d*COUT+o];
    for (int it = 0; it < 64/NPER; ++it) {
        int n0 = ntile*64 + it*NPER;
        __syncthreads();
        for (int e = t; e < NPER*KI; e += 256) {
            int nn = e / KI, ki = e % KI;
            size_t nb = (size_t)b*NN + n0 + nn;
            float v;
            if (ki == 0) v = x[nb];
            else if (ki < CIN) v = sv[nb*HH + ki - 1];
            else if (ki == CIN) v = axx[nb];
            else v = axs[nb*HH + ki - CIN - 1];
            xg_l[nn][ki] = v;
        }
        __syncthreads();
        float acc = bo;
        #pragma unroll 13
        for (int ki = 0; ki < KI; ++ki) acc += xg_l[nsub][ki]*Wb_l[ki*COUT + o];
        partial[((size_t)b*NN + n0 + nsub)*COUT + o] = acc;
    }
}

__global__ __launch_bounds__(256) void k_napply_gate(
    const float* __restrict__ se_g, const float* __restrict__ Wg,
    const float* __restrict__ bias,
    const float* __restrict__ x, const float* __restrict__ state,
    const float* __restrict__ axx, const float* __restrict__ axs,
    const float* __restrict__ partial,
    float* __restrict__ zs, float* __restrict__ rout)
{
    __shared__ float Wn[KI*COG];
    __shared__ float xg_l[8][KI];
    __shared__ float se_l[ET];
    int n = blockIdx.x, t = threadIdx.x;
    if (t < ET) se_l[t] = se_g[n*ET + t];
    __syncthreads();
    for (int e = t; e < KI*COG; e += 256) {
        float acc = 0.f;
        #pragma unroll
        for (int d = 0; d < ET; ++d) acc += se_l[d]*Wg[d*(KI*COG) + e];
        Wn[e] = acc;
    }
    int o = t & (COG-1), bh = t >> 7;
    float bo = 0.f;
    #pragma unroll
    for (int d = 0; d < ET; ++d) bo += se_l[d]*bias[d*COG + o];
    for (int chunk = 0; chunk < 4; ++chunk) {
        __syncthreads();
        for (int e = t; e < 8*KI; e += 256) {
            int bl = e / KI, ki = e % KI;
            size_t nb = (size_t)(chunk*8 + bl)*NN + n;
            float v;
            if (ki == 0) v = x[nb];
            else if (ki < CIN) v = state[nb*HH + ki - 1];
            else if (ki == CIN) v = axx[nb];
            else v = axs[nb*HH + ki - CIN - 1];
            xg_l[bl][ki] = v;
        }
        __syncthreads();
        #pragma unroll
        for (int bq = 0; bq < 4; ++bq) {
            int bl = bq*2 + bh;
            int bb = chunk*8 + bl;
            float acc = bo + partial[((size_t)bb*NN + n)*COG + o];
            #pragma unroll 13
            for (int ki = 0; ki < KI; ++ki) acc += xg_l[bl][ki]*Wn[ki*COG + o];
            float gv = 1.f/(1.f + __expf(-acc));
            size_t base = ((size_t)bb*NN + n)*HH;
            if (o < HH) zs[base + o] = gv * state[base + o];
            else rout[base + o - HH] = gv;
        }
    }
}

__global__ __launch_bounds__(256) void k_napply_upd(
    const float* __restrict__ se_g, const float* __restrict__ Wu,
    const float* __restrict__ bias,
    const float* __restrict__ x, const float* __restrict__ zs,
    const float* __restrict__ axx, const float* __restrict__ axs,
    const float* __restrict__ partial, const float* __restrict__ rin,
    const float* __restrict__ state, float* __restrict__ out)
{
    __shared__ float Wn[KI*COU];
    __shared__ float xg_l[8][KI];
    __shared__ float se_l[ET];
    int n = blockIdx.x, t = threadIdx.x;
    if (t < ET) se_l[t] = se_g[n*ET + t];
    __syncthreads();
    for (int e = t; e < KI*COU; e += 256) {
        float acc = 0.f;
        #pragma unroll
        for (int d = 0; d < ET; ++d) acc += se_l[d]*Wu[d*(KI*COU) + e];
        Wn[e] = acc;
    }
    int o = t & (COU-1), bq4 = t >> 6;
    float bo = 0.f;
    #pragma unroll
    for (int d = 0; d < ET; ++d) bo += se_l[d]*bias[d*COU + o];
    for (int chunk = 0; chunk < 4; ++chunk) {
        __syncthreads();
        for (int e = t; e < 8*KI; e += 256) {
            int bl = e / KI, ki = e % KI;
            size_t nb = (size_t)(chunk*8 + bl)*NN + n;
            float v;
            if (ki == 0) v = x[nb];
            else if (ki < CIN) v = zs[nb*HH + ki - 1];
            else if (ki == CIN) v = axx[nb];
            else v = axs[nb*HH + ki - CIN - 1];
            xg_l[bl][ki] = v;
        }
        __syncthreads();
        #pragma unroll
        for (int bq = 0; bq < 2; ++bq) {
            int bl = bq*4 + bq4;
            int bb = chunk*8 + bl;
            float acc = bo + partial[((size_t)bb*NN + n)*COU + o];
            #pragma unroll 13
            for (int ki = 0; ki < KI; ++ki) acc += xg_l[bl][ki]*Wn[ki*COU + o];
            float hc = tanhf(acc);
            size_t base = ((size_t)bb*NN + n)*HH;
            float rv = rin[base + o];
            out[base + o] = rv*state[base + o] + (1.f - rv)*hc;
        }
    }
}

} // namespace

extern "C" void kernel_launch(void* const* d_in, const int* in_sizes, int n_in,
                              void* d_out, int out_size, void* d_ws, size_t ws_size,
                              hipStream_t stream) {
    const float* x     = (const float*)d_in[0];
    const float* R     = (const float*)d_in[1];
    const float* state = (const float*)d_in[2];
    const float* SC    = (const float*)d_in[3];
    const float* SE    = (const float*)d_in[4];
    const float* W_se  = (const float*)d_in[5];
    const float* b_se  = (const float*)d_in[6];
    const float* T_tod = (const float*)d_in[7];
    const float* T_dow = (const float*)d_in[8];
    const float* W_g   = (const float*)d_in[9];
    const float* b_g   = (const float*)d_in[10];
    const float* W_u   = (const float*)d_in[11];
    const float* b_u   = (const float*)d_in[12];
    const int*   tidx  = (const int*)d_in[13];
    float* out = (float*)d_out;
    float* ws = (float*)d_ws;

    float* se    = ws;                    // 16384
    float* tt    = se + 16384;            // 512
    float* Wbg   = tt + 512;              // 532480
    float* Wbu   = Wbg + 532480;          // 266240
    float* Mr    = Wbu + 266240;          // 32768
    float* Li    = Mr + 32768;            // 32768
    float* axx   = Li + 32768;            // 32768
    float* axgs  = axx + 32768;           // 2097152
    float* axcs  = axgs + 2097152;        // 2097152
    float* zs    = axcs + 2097152;        // 2097152
    float* rr    = zs + 2097152;          // 2097152
    float* pg    = rr + 2097152;          // 4194304
    float* pu    = pg + 4194304;          // 2097152
    unsigned short* stebf = (unsigned short*)(pu + 2097152);   // 524288 ushorts

    k_prep1<<<66, 256, 0, stream>>>(SE, W_se, b_se, T_tod, T_dow, tidx, se, tt);
    k_prep2bf<<<2048, 256, 0, stream>>>(se, tt, stebf);
    k_prep3<<<3120, 256, 0, stream>>>(tt, W_g, W_u, Wbg, Wbu);

    k_attn<1><<<dim3(64, 32), 256, SMEM_BYTES, stream>>>(
        stebf, R, SC, x, state, Mr, Li, axx, axgs);
    k_bapply<COG><<<dim3(16, 32), 256, 0, stream>>>(Wbg, b_g, tt, x, state, axx, axgs, pg);
    k_napply_gate<<<1024, 256, 0, stream>>>(se, W_g, b_g, x, state, axx, axgs, pg, zs, rr);
    k_attn<2><<<dim3(64, 32), 256, SMEM_BYTES, stream>>>(
        stebf, R, SC, x, zs, Mr, Li, axx, axcs);
    k_bapply<COU><<<dim3(16, 32), 256, 0, stream>>>(Wbu, b_u, tt, x, zs, axx, axcs, pu);
    k_napply_upd<<<1024, 256, 0, stream>>>(se, W_u, b_u, x, zs, axx, axcs, pu, rr, state, out);
}

// Round 6
// 329.212 us; speedup vs baseline: 3.8661x; 1.5384x over previous
//
#include <hip/hip_runtime.h>
#include <math.h>

namespace {
constexpr int BB = 32;
constexpr int NN = 1024;
constexpr int ET = 16;
constexpr int HH = 64;
constexpr int CIN = 65;       // Din + HID
constexpr int KI = 2*CIN;     // 130
constexpr int COG = 2*HH;     // 128
constexpr int COU = HH;       // 64
constexpr int PP = 288;
constexpr int FF = 7;
constexpr int FRQ = 12;
constexpr int XK = 160;       // padded K for MFMA (5 x 32)
constexpr int KP = 168;       // row stride for transposed weights (16B-aligned, low-conflict)

typedef __attribute__((ext_vector_type(4))) float f32x4;
typedef __attribute__((ext_vector_type(8))) short s16x8;
typedef unsigned long long ull;

__device__ __forceinline__ float bf2f(unsigned short u) {
    unsigned v = ((unsigned)u) << 16;
    return __builtin_bit_cast(float, v);
}
__device__ __forceinline__ unsigned short f2bf(float f) {
    unsigned u = __builtin_bit_cast(unsigned, f);
    u += 0x7fffu + ((u >> 16) & 1u);   // RNE
    return (unsigned short)(u >> 16);
}

// ---------------- prep kernels ----------------
__global__ void k_prep1(const float* __restrict__ SE, const float* __restrict__ Wse,
                        const float* __restrict__ bse, const float* __restrict__ Ttod,
                        const float* __restrict__ Tdow, const int* __restrict__ tidx,
                        float* __restrict__ se, float* __restrict__ tt) {
    int idx = blockIdx.x*blockDim.x + threadIdx.x;
    if (idx < NN*ET) {
        int n = idx / ET, d = idx % ET;
        float acc = bse[d];
        #pragma unroll
        for (int e = 0; e < ET; ++e) acc += SE[n*ET + e]*Wse[e*ET + d];
        se[idx] = acc;
    } else if (idx < NN*ET + BB*ET) {
        int r = idx - NN*ET;
        int b = r / ET, d = r % ET;
        int t = tidx[b]*FRQ;
        tt[r] = Ttod[(t % PP)*ET + d] + Tdow[((t/PP) % FF)*ET + d];
    }
}

__global__ void k_prep2bf(const float* __restrict__ se, const float* __restrict__ tt,
                          unsigned short* __restrict__ stebf) {
    int idx = blockIdx.x*blockDim.x + threadIdx.x;
    if (idx >= BB*NN*ET) return;
    int d = idx % ET;
    int n = (idx/ET) % NN;
    int b = idx/(ET*NN);
    stebf[idx] = f2bf(se[n*ET+d] + tt[b*ET+d]);
}

// batch weights, bf16 transposed padded: Wbt[b][o][KP], zero for ki>=130
__global__ void k_prep3bt(const float* __restrict__ tt, const float* __restrict__ Wg,
                          const float* __restrict__ Wu,
                          unsigned short* __restrict__ Wbtg, unsigned short* __restrict__ Wbtu) {
    int idx = blockIdx.x*blockDim.x + threadIdx.x;
    constexpr int NG = BB*KP*COG;
    constexpr int NU = BB*KP*COU;
    if (idx < NG) {
        int b = idx/(KP*COG); int r = idx%(KP*COG); int ki = r/COG; int o = r%COG;
        float v = 0.f;
        if (ki < KI) {
            #pragma unroll
            for (int d = 0; d < ET; ++d) v += tt[b*ET+d]*Wg[(d*KI + ki)*COG + o];
        }
        Wbtg[((size_t)b*COG + o)*KP + ki] = f2bf(v);
    } else if (idx < NG + NU) {
        int j = idx - NG;
        int b = j/(KP*COU); int r = j%(KP*COU); int ki = r/COU; int o = r%COU;
        float v = 0.f;
        if (ki < KI) {
            #pragma unroll
            for (int d = 0; d < ET; ++d) v += tt[b*ET+d]*Wu[(d*KI + ki)*COU + o];
        }
        Wbtu[((size_t)b*COU + o)*KP + ki] = f2bf(v);
    }
}

// pack xg = [x, sv, axx, ax2, 0-pad] as bf16 [b*n][XK]
__global__ void k_pack(const float* __restrict__ x, const float* __restrict__ sv,
                       const float* __restrict__ axx, const float* __restrict__ ax2,
                       unsigned short* __restrict__ xgbf) {
    int idx = blockIdx.x*blockDim.x + threadIdx.x;
    if (idx >= BB*NN*(XK/2)) return;
    int row = idx/(XK/2), c = idx%(XK/2);
    float v[2];
    #pragma unroll
    for (int h = 0; h < 2; ++h) {
        int k = 2*c + h;
        float val;
        if (k == 0) val = x[row];
        else if (k < CIN) val = sv[(size_t)row*HH + k - 1];
        else if (k == CIN) val = axx[row];
        else if (k < KI) val = ax2[(size_t)row*HH + k - CIN - 1];
        else val = 0.f;
        v[h] = val;
    }
    ((unsigned*)xgbf)[idx] = ((unsigned)f2bf(v[1]) << 16) | f2bf(v[0]);
}

// ---------------- fused attention pass (unchanged from passing r5) ----------------
constexpr int SSTR   = 1040;
constexpr int S_OFF  = 0;
constexpr int V_OFF  = 33280;
constexpr int VSTR   = 72;
constexpr int XV_OFF = 42496;
constexpr int MSH_OFF  = 46592;
constexpr int MSHC_OFF = 46848;
constexpr int LP_OFF   = 46912;
constexpr int AXP_OFF  = 47168;
constexpr int LSH_OFF  = 47424;
constexpr int SMEM_BYTES = 47488;

template<int PASS>
__global__ __launch_bounds__(256, 3) void k_attn(
    const unsigned short* __restrict__ stebf, const float* __restrict__ Rg,
    const float* __restrict__ SCg, const float* __restrict__ xg,
    const float* __restrict__ Vglob,
    float* __restrict__ Mr, float* __restrict__ Li, float* __restrict__ Axx,
    float* __restrict__ outp)
{
    extern __shared__ char smem[];
    const int t = threadIdx.x, lane = t & 63, w = t >> 6;
    const int c15 = lane & 15, g = lane >> 4;
    const int strip = blockIdx.x, b = blockIdx.y;
    const size_t bN = (size_t)b * NN;
    const int r0 = strip * 16;

    float* Mshf  = (float*)(smem + MSH_OFF);
    float* MshCf = (float*)(smem + MSHC_OFF);
    float* Lpf   = (float*)(smem + LP_OFF);
    float* Axpf  = (float*)(smem + AXP_OFF);
    float* Lshf  = (float*)(smem + LSH_OFF);

    if (PASS == 1) {
        ((float4*)(smem + XV_OFF))[t] = ((const float4*)(xg + bN))[t];
    }

    {   // phase a: scores
        s16x8 af = {0,0,0,0,0,0,0,0};
        if (g < 2) af = *(const s16x8*)(stebf + (bN + r0 + c15)*ET + g*8);
        const float* Rb  = Rg  + (bN + r0 + g*4)*NN;
        const float* SCb = SCg + (size_t)(r0 + g*4)*NN;
        float mx0 = -INFINITY, mx1 = -INFINITY, mx2 = -INFINITY, mx3 = -INFINITY;
        float rc[4], scv[4];
        {
            int col = w*16 + c15;
            #pragma unroll
            for (int q = 0; q < 4; ++q) { rc[q] = Rb[(size_t)q*NN + col]; scv[q] = SCb[(size_t)q*NN + col]; }
        }
        for (int j = 0; j < 16; ++j) {
            int colB = j*64 + w*16 + c15;
            s16x8 bf = {0,0,0,0,0,0,0,0};
            if (g < 2) bf = *(const s16x8*)(stebf + (bN + colB)*ET + g*8);
            float rn[4] = {0.f,0.f,0.f,0.f}, sn[4] = {0.f,0.f,0.f,0.f};
            if (j < 15) {
                int col = colB + 64;
                #pragma unroll
                for (int q = 0; q < 4; ++q) { rn[q] = Rb[(size_t)q*NN + col]; sn[q] = SCb[(size_t)q*NN + col]; }
            }
            f32x4 zero = {0.f,0.f,0.f,0.f};
            f32x4 d = __builtin_amdgcn_mfma_f32_16x16x32_bf16(af, bf, zero, 0, 0, 0);
            #pragma unroll
            for (int q = 0; q < 4; ++q) {
                float s = fmaxf(d[q], 0.f) + rc[q] + scv[q];
                if (PASS == 1) {
                    if (q == 0) mx0 = fmaxf(mx0, s);
                    if (q == 1) mx1 = fmaxf(mx1, s);
                    if (q == 2) mx2 = fmaxf(mx2, s);
                    if (q == 3) mx3 = fmaxf(mx3, s);
                }
                int rowl = g*4 + q;
                *(unsigned short*)(smem + S_OFF + (unsigned)(rowl*SSTR + colB)*2u) = f2bf(s);
            }
            #pragma unroll
            for (int q = 0; q < 4; ++q) { rc[q] = rn[q]; scv[q] = sn[q]; }
        }
        if (PASS == 1) {
            float mxa[4] = {mx0, mx1, mx2, mx3};
            #pragma unroll
            for (int q = 0; q < 4; ++q) {
                float m = mxa[q];
                m = fmaxf(m, __shfl_xor(m, 1));
                m = fmaxf(m, __shfl_xor(m, 2));
                m = fmaxf(m, __shfl_xor(m, 4));
                m = fmaxf(m, __shfl_xor(m, 8));
                if (c15 == 0) Mshf[w*16 + g*4 + q] = m;
            }
        }
    }
    __syncthreads();

    if (PASS == 1) {
        if (t < 16) {
            float m = fmaxf(fmaxf(Mshf[t], Mshf[16+t]), fmaxf(Mshf[32+t], Mshf[48+t]));
            MshCf[t] = m;
            Mr[bN + r0 + t] = m;
        }
    } else {
        if (t < 16) MshCf[t] = Mr[bN + r0 + t];
        if (t >= 64 && t < 80) Lshf[t-64] = Li[bN + r0 + (t-64)];
    }
    __syncthreads();

    {   // phase b
        const int rowl = c15;
        const float m = MshCf[rowl];
        float L = 0.f, ax = 0.f;
        for (int it = 0; it < 16; ++it) {
            int k = w*256 + it*16 + g*4;
            unsigned byteo = (unsigned)(rowl*SSTR + k)*2u;
            ull v = *(ull*)(smem + S_OFF + byteo);
            float s0 = bf2f((unsigned short)v);
            float s1 = bf2f((unsigned short)(v >> 16));
            float s2 = bf2f((unsigned short)(v >> 32));
            float s3 = bf2f((unsigned short)(v >> 48));
            float p0 = __expf(s0 - m), p1 = __expf(s1 - m);
            float p2 = __expf(s2 - m), p3 = __expf(s3 - m);
            if (PASS == 1) {
                float4 xq = *(const float4*)(smem + XV_OFF + k*4);
                L += (p0 + p1) + (p2 + p3);
                ax += p0*xq.x + p1*xq.y + p2*xq.z + p3*xq.w;
            }
            unsigned lo = ((unsigned)f2bf(p1) << 16) | f2bf(p0);
            unsigned hi = ((unsigned)f2bf(p3) << 16) | f2bf(p2);
            *(ull*)(smem + S_OFF + byteo) = ((ull)hi << 32) | lo;
        }
        if (PASS == 1) {
            L += __shfl_xor(L, 16); L += __shfl_xor(L, 32);
            ax += __shfl_xor(ax, 16); ax += __shfl_xor(ax, 32);
            if (g == 0) { Lpf[w*16 + rowl] = L; Axpf[w*16 + rowl] = ax; }
        }
    }
    __syncthreads();
    if (PASS == 1) {
        if (t < 16) {
            float Lt = Lpf[t] + Lpf[16+t] + Lpf[32+t] + Lpf[48+t];
            float li = 1.f / Lt;
            Lshf[t] = li;
            Li[bN + r0 + t] = li;
            Axx[bN + r0 + t] = (Axpf[t] + Axpf[16+t] + Axpf[32+t] + Axpf[48+t]) * li;
        }
        __syncthreads();
    }

    {   // phase c: PV
        f32x4 acc = {0.f,0.f,0.f,0.f};
        const float* Vsrc = Vglob + bN*HH;
        const int chS = t & 63, q4 = t >> 6;
        for (int j = 0; j < 16; ++j) {
            #pragma unroll
            for (int itq = 0; itq < 4; ++itq) {
                int mm0 = itq*16 + q4*4;
                const float* vp = Vsrc + (size_t)(j*64 + mm0)*HH + chS;
                float v0 = vp[0], v1 = vp[HH], v2 = vp[2*HH], v3 = vp[3*HH];
                ull o = (ull)f2bf(v0) | ((ull)f2bf(v1)<<16)
                      | ((ull)f2bf(v2)<<32) | ((ull)f2bf(v3)<<48);
                *(ull*)(smem + V_OFF + (unsigned)(chS*VSTR + mm0)*2u) = o;
            }
            __syncthreads();
            #pragma unroll
            for (int ks = 0; ks < 2; ++ks) {
                s16x8 a  = *(const s16x8*)(smem + S_OFF + (unsigned)(c15*SSTR + j*64 + ks*32 + g*8)*2u);
                s16x8 bv = *(const s16x8*)(smem + V_OFF + (unsigned)((w*16 + c15)*VSTR + ks*32 + g*8)*2u);
                acc = __builtin_amdgcn_mfma_f32_16x16x32_bf16(a, bv, acc, 0, 0, 0);
            }
            __syncthreads();
        }
        #pragma unroll
        for (int q = 0; q < 4; ++q) {
            int rowl = g*4 + q;
            float li = Lshf[rowl];
            outp[(bN + r0 + rowl)*HH + w*16 + c15] = acc[q] * li;
        }
    }
}

// ---------------- MFMA batch-part GEMM: partial[b,n,o] = xg[b,n,:]@Wbt[b] + tt-bias ----------------
template<int COUT>
__global__ __launch_bounds__(256, 2) void k_bapplyM(
    const unsigned short* __restrict__ Wbt, const float* __restrict__ bias,
    const float* __restrict__ tt, const unsigned short* __restrict__ xgbf,
    float* __restrict__ partial)
{
    constexpr int NTP = COUT/64;    // N-tiles per wave (gate 2, upd 1)
    __shared__ __align__(16) unsigned short Wl[COUT*KP];
    const int t = threadIdx.x, lane = t & 63, w = t >> 6;
    const int c15 = lane & 15, g = lane >> 4;
    const int b = blockIdx.y, n0 = blockIdx.x*64;

    {   // stage Wbt[b] (layout-identical copy)
        const unsigned* src = (const unsigned*)(Wbt + (size_t)b*COUT*KP);
        unsigned* dst = (unsigned*)Wl;
        #pragma unroll
        for (int e = t; e < COUT*KP/2; e += 256) dst[e] = src[e];
    }
    __syncthreads();

    f32x4 acc[4][NTP];
    #pragma unroll
    for (int mt = 0; mt < 4; ++mt)
        #pragma unroll
        for (int nt = 0; nt < NTP; ++nt) acc[mt][nt] = (f32x4){0.f,0.f,0.f,0.f};

    for (int ks = 0; ks < 5; ++ks) {
        s16x8 a[4];
        #pragma unroll
        for (int mt = 0; mt < 4; ++mt)
            a[mt] = *(const s16x8*)(xgbf + ((size_t)b*NN + n0 + mt*16 + c15)*XK + ks*32 + g*8);
        #pragma unroll
        for (int nt = 0; nt < NTP; ++nt) {
            int o = (w*NTP + nt)*16 + c15;
            s16x8 bf = *(const s16x8*)(Wl + o*KP + ks*32 + g*8);
            #pragma unroll
            for (int mt = 0; mt < 4; ++mt)
                acc[mt][nt] = __builtin_amdgcn_mfma_f32_16x16x32_bf16(a[mt], bf, acc[mt][nt], 0, 0, 0);
        }
    }

    #pragma unroll
    for (int nt = 0; nt < NTP; ++nt) {
        int o = (w*NTP + nt)*16 + c15;
        float bo = 0.f;
        #pragma unroll
        for (int d = 0; d < ET; ++d) bo += tt[b*ET+d]*bias[d*COUT+o];
        #pragma unroll
        for (int mt = 0; mt < 4; ++mt)
            #pragma unroll
            for (int q = 0; q < 4; ++q)
                partial[((size_t)b*NN + n0 + mt*16 + g*4 + q)*COUT + o] = acc[mt][nt][q] + bo;
    }
}

// ---------------- MFMA node-part + gate epilogue ----------------
__global__ __launch_bounds__(256, 2) void k_napplyM_gate(
    const float* __restrict__ se_g, const float* __restrict__ Wg,
    const float* __restrict__ bias, const unsigned short* __restrict__ xgbf,
    const float* __restrict__ partial, const float* __restrict__ state,
    float* __restrict__ zs, float* __restrict__ rout)
{
    __shared__ __align__(16) unsigned short Wnt[COG*KP];
    __shared__ float se_l[ET];
    const int t = threadIdx.x, lane = t & 63, w = t >> 6;
    const int c15 = lane & 15, g = lane >> 4;
    const int n = blockIdx.x;
    if (t < ET) se_l[t] = se_g[n*ET + t];
    __syncthreads();

    for (int e = t; e < COG*KP; e += 256) {
        int ki = e/COG, o = e%COG;
        float v = 0.f;
        if (ki < KI) {
            #pragma unroll
            for (int d = 0; d < ET; ++d) v += se_l[d]*Wg[(d*KI + ki)*COG + o];
        }
        Wnt[o*KP + ki] = f2bf(v);
    }
    __syncthreads();

    f32x4 acc[2][2];
    #pragma unroll
    for (int mt = 0; mt < 2; ++mt)
        #pragma unroll
        for (int nt = 0; nt < 2; ++nt) acc[mt][nt] = (f32x4){0.f,0.f,0.f,0.f};

    for (int ks = 0; ks < 5; ++ks) {
        s16x8 a[2];
        #pragma unroll
        for (int mt = 0; mt < 2; ++mt)
            a[mt] = *(const s16x8*)(xgbf + ((size_t)(mt*16 + c15)*NN + n)*XK + ks*32 + g*8);
        #pragma unroll
        for (int nt = 0; nt < 2; ++nt) {
            int o = (w*2 + nt)*16 + c15;
            s16x8 bf = *(const s16x8*)(Wnt + o*KP + ks*32 + g*8);
            #pragma unroll
            for (int mt = 0; mt < 2; ++mt)
                acc[mt][nt] = __builtin_amdgcn_mfma_f32_16x16x32_bf16(a[mt], bf, acc[mt][nt], 0, 0, 0);
        }
    }

    #pragma unroll
    for (int nt = 0; nt < 2; ++nt) {
        int o = (w*2 + nt)*16 + c15;
        float bo = 0.f;
        #pragma unroll
        for (int d = 0; d < ET; ++d) bo += se_l[d]*bias[d*COG + o];
        #pragma unroll
        for (int mt = 0; mt < 2; ++mt)
            #pragma unroll
            for (int q = 0; q < 4; ++q) {
                int b = mt*16 + g*4 + q;
                size_t bn = (size_t)b*NN + n;
                float v = acc[mt][nt][q] + bo + partial[bn*COG + o];
                float gv = 1.f/(1.f + __expf(-v));
                if (o < HH) zs[bn*HH + o] = gv * state[bn*HH + o];
                else rout[bn*HH + o - HH] = gv;
            }
    }
}

// ---------------- MFMA node-part + upd epilogue ----------------
__global__ __launch_bounds__(256, 2) void k_napplyM_upd(
    const float* __restrict__ se_g, const float* __restrict__ Wu,
    const float* __restrict__ bias, const unsigned short* __restrict__ xgbf,
    const float* __restrict__ partial, const float* __restrict__ rin,
    const float* __restrict__ state, float* __restrict__ out)
{
    __shared__ __align__(16) unsigned short Wnt[COU*KP];
    __shared__ float se_l[ET];
    const int t = threadIdx.x, lane = t & 63, w = t >> 6;
    const int c15 = lane & 15, g = lane >> 4;
    const int n = blockIdx.x;
    if (t < ET) se_l[t] = se_g[n*ET + t];
    __syncthreads();

    for (int e = t; e < COU*KP; e += 256) {
        int ki = e/COU, o = e%COU;
        float v = 0.f;
        if (ki < KI) {
            #pragma unroll
            for (int d = 0; d < ET; ++d) v += se_l[d]*Wu[(d*KI + ki)*COU + o];
        }
        Wnt[o*KP + ki] = f2bf(v);
    }
    __syncthreads();

    f32x4 acc[2];
    acc[0] = (f32x4){0.f,0.f,0.f,0.f};
    acc[1] = (f32x4){0.f,0.f,0.f,0.f};

    for (int ks = 0; ks < 5; ++ks) {
        s16x8 a[2];
        #pragma unroll
        for (int mt = 0; mt < 2; ++mt)
            a[mt] = *(const s16x8*)(xgbf + ((size_t)(mt*16 + c15)*NN + n)*XK + ks*32 + g*8);
        int o = w*16 + c15;
        s16x8 bf = *(const s16x8*)(Wnt + o*KP + ks*32 + g*8);
        #pragma unroll
        for (int mt = 0; mt < 2; ++mt)
            acc[mt] = __builtin_amdgcn_mfma_f32_16x16x32_bf16(a[mt], bf, acc[mt], 0, 0, 0);
    }

    {
        int o = w*16 + c15;
        float bo = 0.f;
        #pragma unroll
        for (int d = 0; d < ET; ++d) bo += se_l[d]*bias[d*COU + o];
        #pragma unroll
        for (int mt = 0; mt < 2; ++mt)
            #pragma unroll
            for (int q = 0; q < 4; ++q) {
                int b = mt*16 + g*4 + q;
                size_t bn = (size_t)b*NN + n;
                float v = acc[mt][q] + bo + partial[bn*COU + o];
                float hc = tanhf(v);
                float rv = rin[bn*HH + o];
                out[bn*HH + o] = rv*state[bn*HH + o] + (1.f - rv)*hc;
            }
    }
}

} // namespace

extern "C" void kernel_launch(void* const* d_in, const int* in_sizes, int n_in,
                              void* d_out, int out_size, void* d_ws, size_t ws_size,
                              hipStream_t stream) {
    const float* x     = (const float*)d_in[0];
    const float* R     = (const float*)d_in[1];
    const float* state = (const float*)d_in[2];
    const float* SC    = (const float*)d_in[3];
    const float* SE    = (const float*)d_in[4];
    const float* W_se  = (const float*)d_in[5];
    const float* b_se  = (const float*)d_in[6];
    const float* T_tod = (const float*)d_in[7];
    const float* T_dow = (const float*)d_in[8];
    const float* W_g   = (const float*)d_in[9];
    const float* b_g   = (const float*)d_in[10];
    const float* W_u   = (const float*)d_in[11];
    const float* b_u   = (const float*)d_in[12];
    const int*   tidx  = (const int*)d_in[13];
    float* out = (float*)d_out;
    float* ws = (float*)d_ws;

    // float-slot layout, total ~56 MB (< 64.5 MB proven footprint)
    float* se    = ws;                    // 16384
    float* tt    = se + 16384;            // 512
    float* Mr    = tt + 512;              // 32768
    float* Li    = Mr + 32768;            // 32768
    float* axx   = Li + 32768;            // 32768
    float* axgs  = axx + 32768;           // 2097152 (reused as axcs)
    float* zs    = axgs + 2097152;        // 2097152
    float* rr    = zs + 2097152;          // 2097152
    float* pg    = rr + 2097152;          // 4194304 (reused as pu)
    unsigned short* stebf = (unsigned short*)(pg + 4194304);  // 524288 us
    unsigned short* Wbtg  = stebf + 524288;                   // 688128 us
    unsigned short* Wbtu  = Wbtg + 688128;                    // 344064 us
    unsigned short* xgbf  = Wbtu + 344064;                    // 5242880 us
    float* axcs = axgs;
    float* pu   = pg;

    k_prep1<<<66, 256, 0, stream>>>(SE, W_se, b_se, T_tod, T_dow, tidx, se, tt);
    k_prep2bf<<<2048, 256, 0, stream>>>(se, tt, stebf);
    k_prep3bt<<<4032, 256, 0, stream>>>(tt, W_g, W_u, Wbtg, Wbtu);

    k_attn<1><<<dim3(64, 32), 256, SMEM_BYTES, stream>>>(
        stebf, R, SC, x, state, Mr, Li, axx, axgs);
    k_pack<<<10240, 256, 0, stream>>>(x, state, axx, axgs, xgbf);
    k_bapplyM<COG><<<dim3(16, 32), 256, 0, stream>>>(Wbtg, b_g, tt, xgbf, pg);
    k_napplyM_gate<<<1024, 256, 0, stream>>>(se, W_g, b_g, xgbf, pg, state, zs, rr);

    k_attn<2><<<dim3(64, 32), 256, SMEM_BYTES, stream>>>(
        stebf, R, SC, x, zs, Mr, Li, axx, axcs);
    k_pack<<<10240, 256, 0, stream>>>(x, zs, axx, axcs, xgbf);
    k_bapplyM<COU><<<dim3(16, 32), 256, 0, stream>>>(Wbtu, b_u, tt, xgbf, pu);
    k_napplyM_upd<<<1024, 256, 0, stream>>>(se, W_u, b_u, xgbf, pu, rr, state, out);
}

// Round 7
// 268.156 us; speedup vs baseline: 4.7464x; 1.2277x over previous
//
#include <hip/hip_runtime.h>
#include <math.h>

namespace {
constexpr int BB = 32;
constexpr int NN = 1024;
constexpr int ET = 16;
constexpr int HH = 64;
constexpr int CIN = 65;       // Din + HID
constexpr int KI = 2*CIN;     // 130
constexpr int COG = 2*HH;     // 128
constexpr int COU = HH;       // 64
constexpr int PP = 288;
constexpr int FF = 7;
constexpr int FRQ = 12;
constexpr int XK = 160;       // padded K for MFMA (5 x 32)
constexpr int KP = 168;       // row stride for transposed weights

typedef __attribute__((ext_vector_type(4))) float f32x4;
typedef __attribute__((ext_vector_type(8))) short s16x8;
typedef unsigned long long ull;

__device__ __forceinline__ float bf2f(unsigned short u) {
    unsigned v = ((unsigned)u) << 16;
    return __builtin_bit_cast(float, v);
}
__device__ __forceinline__ unsigned short f2bf(float f) {
    unsigned u = __builtin_bit_cast(unsigned, f);
    u += 0x7fffu + ((u >> 16) & 1u);   // RNE
    return (unsigned short)(u >> 16);
}

// ---------------- prep kernels ----------------
__global__ void k_prep1(const float* __restrict__ SE, const float* __restrict__ Wse,
                        const float* __restrict__ bse, const float* __restrict__ Ttod,
                        const float* __restrict__ Tdow, const int* __restrict__ tidx,
                        float* __restrict__ se, float* __restrict__ tt) {
    int idx = blockIdx.x*blockDim.x + threadIdx.x;
    if (idx < NN*ET) {
        int n = idx / ET, d = idx % ET;
        float acc = bse[d];
        #pragma unroll
        for (int e = 0; e < ET; ++e) acc += SE[n*ET + e]*Wse[e*ET + d];
        se[idx] = acc;
    } else if (idx < NN*ET + BB*ET) {
        int r = idx - NN*ET;
        int b = r / ET, d = r % ET;
        int t = tidx[b]*FRQ;
        tt[r] = Ttod[(t % PP)*ET + d] + Tdow[((t/PP) % FF)*ET + d];
    }
}

__global__ void k_prep2bf(const float* __restrict__ se, const float* __restrict__ tt,
                          unsigned short* __restrict__ stebf) {
    int idx = blockIdx.x*blockDim.x + threadIdx.x;
    if (idx >= BB*NN*ET) return;
    int d = idx % ET;
    int n = (idx/ET) % NN;
    int b = idx/(ET*NN);
    stebf[idx] = f2bf(se[n*ET+d] + tt[b*ET+d]);
}

// batch weights, bf16 transposed padded: Wbt[b][o][KP]
__global__ void k_prep3bt(const float* __restrict__ tt, const float* __restrict__ Wg,
                          const float* __restrict__ Wu,
                          unsigned short* __restrict__ Wbtg, unsigned short* __restrict__ Wbtu) {
    int idx = blockIdx.x*blockDim.x + threadIdx.x;
    constexpr int NG = BB*KP*COG;
    constexpr int NU = BB*KP*COU;
    if (idx < NG) {
        int b = idx/(KP*COG); int r = idx%(KP*COG); int ki = r/COG; int o = r%COG;
        float v = 0.f;
        if (ki < KI) {
            #pragma unroll
            for (int d = 0; d < ET; ++d) v += tt[b*ET+d]*Wg[(d*KI + ki)*COG + o];
        }
        Wbtg[((size_t)b*COG + o)*KP + ki] = f2bf(v);
    } else if (idx < NG + NU) {
        int j = idx - NG;
        int b = j/(KP*COU); int r = j%(KP*COU); int ki = r/COU; int o = r%COU;
        float v = 0.f;
        if (ki < KI) {
            #pragma unroll
            for (int d = 0; d < ET; ++d) v += tt[b*ET+d]*Wu[(d*KI + ki)*COU + o];
        }
        Wbtu[((size_t)b*COU + o)*KP + ki] = f2bf(v);
    }
}

// pack xg = [x, sv, axx, ax2, 0-pad] as bf16 [b*n][XK]
__global__ void k_pack(const float* __restrict__ x, const float* __restrict__ sv,
                       const float* __restrict__ axx, const float* __restrict__ ax2,
                       unsigned short* __restrict__ xgbf) {
    int idx = blockIdx.x*blockDim.x + threadIdx.x;
    if (idx >= BB*NN*(XK/2)) return;
    int row = idx/(XK/2), c = idx%(XK/2);
    float v[2];
    #pragma unroll
    for (int h = 0; h < 2; ++h) {
        int k = 2*c + h;
        float val;
        if (k == 0) val = x[row];
        else if (k < CIN) val = sv[(size_t)row*HH + k - 1];
        else if (k == CIN) val = axx[row];
        else if (k < KI) val = ax2[(size_t)row*HH + k - CIN - 1];
        else val = 0.f;
        v[h] = val;
    }
    ((unsigned*)xgbf)[idx] = ((unsigned)f2bf(v[1]) << 16) | f2bf(v[0]);
}

// V f32 [b][n][64] -> vt bf16 [b][mb][och][8]  (mb = n/8)
__global__ void k_cvtVt(const float* __restrict__ V, unsigned short* __restrict__ vt) {
    int idx = blockIdx.x*blockDim.x + threadIdx.x;
    if (idx >= BB*128*64) return;
    int och = idx & 63, mb = (idx >> 6) & 127, b = idx >> 13;
    const float* src = V + ((size_t)b*NN + mb*8)*HH + och;
    float v0=src[0], v1=src[HH], v2=src[2*HH], v3=src[3*HH];
    float v4=src[4*HH], v5=src[5*HH], v6=src[6*HH], v7=src[7*HH];
    ull lo = (ull)f2bf(v0) | ((ull)f2bf(v1)<<16) | ((ull)f2bf(v2)<<32) | ((ull)f2bf(v3)<<48);
    ull hi = (ull)f2bf(v4) | ((ull)f2bf(v5)<<16) | ((ull)f2bf(v6)<<32) | ((ull)f2bf(v7)<<48);
    ull* dst = (ull*)(vt + (size_t)idx*8);
    dst[0] = lo; dst[1] = hi;
}

// ---------------- fused attention pass ----------------
constexpr int SSTR   = 1048;       // 524 dwords = 12 mod 32 -> 4-way max banks
constexpr int S_OFF  = 0;          // 16*1048*2 = 33536
constexpr int XV_OFF = 33536;      // 4096
constexpr int MSH_OFF  = 37632;    // 256
constexpr int MSHC_OFF = 37888;    // 64
constexpr int LP_OFF   = 37952;    // 256
constexpr int AXP_OFF  = 38208;    // 256
constexpr int LSH_OFF  = 38464;    // 64
constexpr int SMEM_BYTES = 38528;  // 4 blocks/CU

template<int PASS>
__global__ __launch_bounds__(256, 4) void k_attn(
    const unsigned short* __restrict__ stebf, const float* __restrict__ Rg,
    const float* __restrict__ SCg, const float* __restrict__ xg,
    const unsigned short* __restrict__ vt,
    float* __restrict__ Mr, float* __restrict__ Li, float* __restrict__ Axx,
    float* __restrict__ outp)
{
    extern __shared__ char smem[];
    const int t = threadIdx.x, lane = t & 63, w = t >> 6;
    const int c15 = lane & 15, g = lane >> 4;
    const int strip = blockIdx.x, b = blockIdx.y;
    const size_t bN = (size_t)b * NN;
    const int r0 = strip * 16;

    float* Mshf  = (float*)(smem + MSH_OFF);
    float* MshCf = (float*)(smem + MSHC_OFF);
    float* Lpf   = (float*)(smem + LP_OFF);
    float* Axpf  = (float*)(smem + AXP_OFF);
    float* Lshf  = (float*)(smem + LSH_OFF);

    if (PASS == 1) {
        ((float4*)(smem + XV_OFF))[t] = ((const float4*)(xg + bN))[t];
    }

    {   // phase a: scores via MFMA
        s16x8 af = {0,0,0,0,0,0,0,0};
        if (g < 2) af = *(const s16x8*)(stebf + (bN + r0 + c15)*ET + g*8);
        const float* Rb  = Rg  + (bN + r0 + g*4)*NN;
        const float* SCb = SCg + (size_t)(r0 + g*4)*NN;
        float mx0 = -INFINITY, mx1 = -INFINITY, mx2 = -INFINITY, mx3 = -INFINITY;
        float rc[4], scv[4];
        {
            int col = w*16 + c15;
            #pragma unroll
            for (int q = 0; q < 4; ++q) { rc[q] = Rb[(size_t)q*NN + col]; scv[q] = SCb[(size_t)q*NN + col]; }
        }
        for (int j = 0; j < 16; ++j) {
            int colB = j*64 + w*16 + c15;
            s16x8 bf = {0,0,0,0,0,0,0,0};
            if (g < 2) bf = *(const s16x8*)(stebf + (bN + colB)*ET + g*8);
            float rn[4] = {0.f,0.f,0.f,0.f}, sn[4] = {0.f,0.f,0.f,0.f};
            if (j < 15) {
                int col = colB + 64;
                #pragma unroll
                for (int q = 0; q < 4; ++q) { rn[q] = Rb[(size_t)q*NN + col]; sn[q] = SCb[(size_t)q*NN + col]; }
            }
            f32x4 zero = {0.f,0.f,0.f,0.f};
            f32x4 d = __builtin_amdgcn_mfma_f32_16x16x32_bf16(af, bf, zero, 0, 0, 0);
            #pragma unroll
            for (int q = 0; q < 4; ++q) {
                float s = fmaxf(d[q], 0.f) + rc[q] + scv[q];
                if (PASS == 1) {
                    if (q == 0) mx0 = fmaxf(mx0, s);
                    if (q == 1) mx1 = fmaxf(mx1, s);
                    if (q == 2) mx2 = fmaxf(mx2, s);
                    if (q == 3) mx3 = fmaxf(mx3, s);
                }
                int rowl = g*4 + q;
                *(unsigned short*)(smem + S_OFF + (unsigned)(rowl*SSTR + colB)*2u) = f2bf(s);
            }
            #pragma unroll
            for (int q = 0; q < 4; ++q) { rc[q] = rn[q]; scv[q] = sn[q]; }
        }
        if (PASS == 1) {
            float mxa[4] = {mx0, mx1, mx2, mx3};
            #pragma unroll
            for (int q = 0; q < 4; ++q) {
                float m = mxa[q];
                m = fmaxf(m, __shfl_xor(m, 1));
                m = fmaxf(m, __shfl_xor(m, 2));
                m = fmaxf(m, __shfl_xor(m, 4));
                m = fmaxf(m, __shfl_xor(m, 8));
                if (c15 == 0) Mshf[w*16 + g*4 + q] = m;
            }
        }
    }
    __syncthreads();

    if (PASS == 1) {
        if (t < 16) {
            float m = fmaxf(fmaxf(Mshf[t], Mshf[16+t]), fmaxf(Mshf[32+t], Mshf[48+t]));
            MshCf[t] = m;
            Mr[bN + r0 + t] = m;
        }
    } else {
        if (t < 16) MshCf[t] = Mr[bN + r0 + t];
        if (t >= 64 && t < 80) Lshf[t-64] = Li[bN + r0 + (t-64)];
    }
    __syncthreads();

    {   // phase b: exp in place (+ L, axx on PASS1)
        const int rowl = c15;
        const float m = MshCf[rowl];
        float L = 0.f, ax = 0.f;
        for (int it = 0; it < 16; ++it) {
            int k = w*256 + it*16 + g*4;
            unsigned byteo = (unsigned)(rowl*SSTR + k)*2u;
            ull v = *(ull*)(smem + S_OFF + byteo);
            float s0 = bf2f((unsigned short)v);
            float s1 = bf2f((unsigned short)(v >> 16));
            float s2 = bf2f((unsigned short)(v >> 32));
            float s3 = bf2f((unsigned short)(v >> 48));
            float p0 = __expf(s0 - m), p1 = __expf(s1 - m);
            float p2 = __expf(s2 - m), p3 = __expf(s3 - m);
            if (PASS == 1) {
                float4 xq = *(const float4*)(smem + XV_OFF + k*4);
                L += (p0 + p1) + (p2 + p3);
                ax += p0*xq.x + p1*xq.y + p2*xq.z + p3*xq.w;
            }
            unsigned lo = ((unsigned)f2bf(p1) << 16) | f2bf(p0);
            unsigned hi = ((unsigned)f2bf(p3) << 16) | f2bf(p2);
            *(ull*)(smem + S_OFF + byteo) = ((ull)hi << 32) | lo;
        }
        if (PASS == 1) {
            L += __shfl_xor(L, 16); L += __shfl_xor(L, 32);
            ax += __shfl_xor(ax, 16); ax += __shfl_xor(ax, 32);
            if (g == 0) { Lpf[w*16 + rowl] = L; Axpf[w*16 + rowl] = ax; }
        }
    }
    __syncthreads();
    if (PASS == 1) {
        if (t < 16) {
            float Lt = Lpf[t] + Lpf[16+t] + Lpf[32+t] + Lpf[48+t];
            float li = 1.f / Lt;
            Lshf[t] = li;
            Li[bN + r0 + t] = li;
            Axx[bN + r0 + t] = (Axpf[t] + Axpf[16+t] + Axpf[32+t] + Axpf[48+t]) * li;
        }
        __syncthreads();
    }

    {   // phase c: PV via MFMA; A from LDS, B direct from global vt; no barriers
        f32x4 acc = {0.f,0.f,0.f,0.f};
        const unsigned short* vtb = vt + ((size_t)b*128*64 + (w*16 + c15))*8;
        #pragma unroll 4
        for (int j = 0; j < 16; ++j) {
            #pragma unroll
            for (int ks = 0; ks < 2; ++ks) {
                s16x8 a  = *(const s16x8*)(smem + S_OFF + (unsigned)(c15*SSTR + j*64 + ks*32 + g*8)*2u);
                s16x8 bv = *(const s16x8*)(vtb + (size_t)(j*8 + ks*4 + g)*512);
                acc = __builtin_amdgcn_mfma_f32_16x16x32_bf16(a, bv, acc, 0, 0, 0);
            }
        }
        #pragma unroll
        for (int q = 0; q < 4; ++q) {
            int rowl = g*4 + q;
            float li = Lshf[rowl];
            outp[(bN + r0 + rowl)*HH + w*16 + c15] = acc[q] * li;
        }
    }
}

// ---------------- MFMA batch-part GEMM ----------------
template<int COUT>
__global__ __launch_bounds__(256, 2) void k_bapplyM(
    const unsigned short* __restrict__ Wbt, const float* __restrict__ bias,
    const float* __restrict__ tt, const unsigned short* __restrict__ xgbf,
    float* __restrict__ partial)
{
    constexpr int NTP = COUT/64;
    __shared__ __align__(16) unsigned short Wl[COUT*KP];
    const int t = threadIdx.x, lane = t & 63, w = t >> 6;
    const int c15 = lane & 15, g = lane >> 4;
    const int b = blockIdx.y, n0 = blockIdx.x*64;

    {
        const unsigned* src = (const unsigned*)(Wbt + (size_t)b*COUT*KP);
        unsigned* dst = (unsigned*)Wl;
        #pragma unroll
        for (int e = t; e < COUT*KP/2; e += 256) dst[e] = src[e];
    }
    __syncthreads();

    f32x4 acc[4][NTP];
    #pragma unroll
    for (int mt = 0; mt < 4; ++mt)
        #pragma unroll
        for (int nt = 0; nt < NTP; ++nt) acc[mt][nt] = (f32x4){0.f,0.f,0.f,0.f};

    for (int ks = 0; ks < 5; ++ks) {
        s16x8 a[4];
        #pragma unroll
        for (int mt = 0; mt < 4; ++mt)
            a[mt] = *(const s16x8*)(xgbf + ((size_t)b*NN + n0 + mt*16 + c15)*XK + ks*32 + g*8);
        #pragma unroll
        for (int nt = 0; nt < NTP; ++nt) {
            int o = (w*NTP + nt)*16 + c15;
            s16x8 bf = *(const s16x8*)(Wl + o*KP + ks*32 + g*8);
            #pragma unroll
            for (int mt = 0; mt < 4; ++mt)
                acc[mt][nt] = __builtin_amdgcn_mfma_f32_16x16x32_bf16(a[mt], bf, acc[mt][nt], 0, 0, 0);
        }
    }

    #pragma unroll
    for (int nt = 0; nt < NTP; ++nt) {
        int o = (w*NTP + nt)*16 + c15;
        float bo = 0.f;
        #pragma unroll
        for (int d = 0; d < ET; ++d) bo += tt[b*ET+d]*bias[d*COUT+o];
        #pragma unroll
        for (int mt = 0; mt < 4; ++mt)
            #pragma unroll
            for (int q = 0; q < 4; ++q)
                partial[((size_t)b*NN + n0 + mt*16 + g*4 + q)*COUT + o] = acc[mt][nt][q] + bo;
    }
}

// ---------------- MFMA node-part + gate epilogue ----------------
__global__ __launch_bounds__(256, 2) void k_napplyM_gate(
    const float* __restrict__ se_g, const float* __restrict__ Wg,
    const float* __restrict__ bias, const unsigned short* __restrict__ xgbf,
    const float* __restrict__ partial, const float* __restrict__ state,
    float* __restrict__ zs, float* __restrict__ rout)
{
    __shared__ __align__(16) unsigned short Wnt[COG*KP];
    __shared__ float se_l[ET];
    const int t = threadIdx.x, lane = t & 63, w = t >> 6;
    const int c15 = lane & 15, g = lane >> 4;
    const int n = blockIdx.x;
    if (t < ET) se_l[t] = se_g[n*ET + t];
    __syncthreads();

    for (int e = t; e < COG*KP; e += 256) {
        int ki = e/COG, o = e%COG;
        float v = 0.f;
        if (ki < KI) {
            #pragma unroll
            for (int d = 0; d < ET; ++d) v += se_l[d]*Wg[(d*KI + ki)*COG + o];
        }
        Wnt[o*KP + ki] = f2bf(v);
    }
    __syncthreads();

    f32x4 acc[2][2];
    #pragma unroll
    for (int mt = 0; mt < 2; ++mt)
        #pragma unroll
        for (int nt = 0; nt < 2; ++nt) acc[mt][nt] = (f32x4){0.f,0.f,0.f,0.f};

    for (int ks = 0; ks < 5; ++ks) {
        s16x8 a[2];
        #pragma unroll
        for (int mt = 0; mt < 2; ++mt)
            a[mt] = *(const s16x8*)(xgbf + ((size_t)(mt*16 + c15)*NN + n)*XK + ks*32 + g*8);
        #pragma unroll
        for (int nt = 0; nt < 2; ++nt) {
            int o = (w*2 + nt)*16 + c15;
            s16x8 bf = *(const s16x8*)(Wnt + o*KP + ks*32 + g*8);
            #pragma unroll
            for (int mt = 0; mt < 2; ++mt)
                acc[mt][nt] = __builtin_amdgcn_mfma_f32_16x16x32_bf16(a[mt], bf, acc[mt][nt], 0, 0, 0);
        }
    }

    #pragma unroll
    for (int nt = 0; nt < 2; ++nt) {
        int o = (w*2 + nt)*16 + c15;
        float bo = 0.f;
        #pragma unroll
        for (int d = 0; d < ET; ++d) bo += se_l[d]*bias[d*COG + o];
        #pragma unroll
        for (int mt = 0; mt < 2; ++mt)
            #pragma unroll
            for (int q = 0; q < 4; ++q) {
                int b = mt*16 + g*4 + q;
                size_t bn = (size_t)b*NN + n;
                float v = acc[mt][nt][q] + bo + partial[bn*COG + o];
                float gv = 1.f/(1.f + __expf(-v));
                if (o < HH) zs[bn*HH + o] = gv * state[bn*HH + o];
                else rout[bn*HH + o - HH] = gv;
            }
    }
}

// ---------------- MFMA node-part + upd epilogue ----------------
__global__ __launch_bounds__(256, 2) void k_napplyM_upd(
    const float* __restrict__ se_g, const float* __restrict__ Wu,
    const float* __restrict__ bias, const unsigned short* __restrict__ xgbf,
    const float* __restrict__ partial, const float* __restrict__ rin,
    const float* __restrict__ state, float* __restrict__ out)
{
    __shared__ __align__(16) unsigned short Wnt[COU*KP];
    __shared__ float se_l[ET];
    const int t = threadIdx.x, lane = t & 63, w = t >> 6;
    const int c15 = lane & 15, g = lane >> 4;
    const int n = blockIdx.x;
    if (t < ET) se_l[t] = se_g[n*ET + t];
    __syncthreads();

    for (int e = t; e < COU*KP; e += 256) {
        int ki = e/COU, o = e%COU;
        float v = 0.f;
        if (ki < KI) {
            #pragma unroll
            for (int d = 0; d < ET; ++d) v += se_l[d]*Wu[(d*KI + ki)*COU + o];
        }
        Wnt[o*KP + ki] = f2bf(v);
    }
    __syncthreads();

    f32x4 acc[2];
    acc[0] = (f32x4){0.f,0.f,0.f,0.f};
    acc[1] = (f32x4){0.f,0.f,0.f,0.f};

    for (int ks = 0; ks < 5; ++ks) {
        s16x8 a[2];
        #pragma unroll
        for (int mt = 0; mt < 2; ++mt)
            a[mt] = *(const s16x8*)(xgbf + ((size_t)(mt*16 + c15)*NN + n)*XK + ks*32 + g*8);
        int o = w*16 + c15;
        s16x8 bf = *(const s16x8*)(Wnt + o*KP + ks*32 + g*8);
        #pragma unroll
        for (int mt = 0; mt < 2; ++mt)
            acc[mt] = __builtin_amdgcn_mfma_f32_16x16x32_bf16(a[mt], bf, acc[mt], 0, 0, 0);
    }

    {
        int o = w*16 + c15;
        float bo = 0.f;
        #pragma unroll
        for (int d = 0; d < ET; ++d) bo += se_l[d]*bias[d*COU + o];
        #pragma unroll
        for (int mt = 0; mt < 2; ++mt)
            #pragma unroll
            for (int q = 0; q < 4; ++q) {
                int b = mt*16 + g*4 + q;
                size_t bn = (size_t)b*NN + n;
                float v = acc[mt][q] + bo + partial[bn*COU + o];
                float hc = tanhf(v);
                float rv = rin[bn*HH + o];
                out[bn*HH + o] = rv*state[bn*HH + o] + (1.f - rv)*hc;
            }
    }
}

} // namespace

extern "C" void kernel_launch(void* const* d_in, const int* in_sizes, int n_in,
                              void* d_out, int out_size, void* d_ws, size_t ws_size,
                              hipStream_t stream) {
    const float* x     = (const float*)d_in[0];
    const float* R     = (const float*)d_in[1];
    const float* state = (const float*)d_in[2];
    const float* SC    = (const float*)d_in[3];
    const float* SE    = (const float*)d_in[4];
    const float* W_se  = (const float*)d_in[5];
    const float* b_se  = (const float*)d_in[6];
    const float* T_tod = (const float*)d_in[7];
    const float* T_dow = (const float*)d_in[8];
    const float* W_g   = (const float*)d_in[9];
    const float* b_g   = (const float*)d_in[10];
    const float* W_u   = (const float*)d_in[11];
    const float* b_u   = (const float*)d_in[12];
    const int*   tidx  = (const int*)d_in[13];
    float* out = (float*)d_out;
    float* ws = (float*)d_ws;

    // ~59.5 MB total (< 64.5 MB proven footprint)
    float* se    = ws;                    // 16384
    float* tt    = se + 16384;            // 512
    float* Mr    = tt + 512;              // 32768
    float* Li    = Mr + 32768;            // 32768
    float* axx   = Li + 32768;            // 32768
    float* axgs  = axx + 32768;           // 2097152 (reused as axcs)
    float* zs    = axgs + 2097152;        // 2097152
    float* rr    = zs + 2097152;          // 2097152
    float* pg    = rr + 2097152;          // 4194304 (reused as pu)
    unsigned short* stebf = (unsigned short*)(pg + 4194304);  // 524288 us
    unsigned short* Wbtg  = stebf + 524288;                   // 688128 us
    unsigned short* Wbtu  = Wbtg + 688128;                    // 344064 us
    unsigned short* xgbf  = Wbtu + 344064;                    // 5242880 us
    unsigned short* vt    = xgbf + 5242880;                   // 2097152 us
    float* axcs = axgs;
    float* pu   = pg;

    k_prep1<<<66, 256, 0, stream>>>(SE, W_se, b_se, T_tod, T_dow, tidx, se, tt);
    k_prep2bf<<<2048, 256, 0, stream>>>(se, tt, stebf);
    k_prep3bt<<<4032, 256, 0, stream>>>(tt, W_g, W_u, Wbtg, Wbtu);

    k_cvtVt<<<1024, 256, 0, stream>>>(state, vt);
    k_attn<1><<<dim3(64, 32), 256, SMEM_BYTES, stream>>>(
        stebf, R, SC, x, vt, Mr, Li, axx, axgs);
    k_pack<<<10240, 256, 0, stream>>>(x, state, axx, axgs, xgbf);
    k_bapplyM<COG><<<dim3(16, 32), 256, 0, stream>>>(Wbtg, b_g, tt, xgbf, pg);
    k_napplyM_gate<<<1024, 256, 0, stream>>>(se, W_g, b_g, xgbf, pg, state, zs, rr);

    k_cvtVt<<<1024, 256, 0, stream>>>(zs, vt);
    k_attn<2><<<dim3(64, 32), 256, SMEM_BYTES, stream>>>(
        stebf, R, SC, x, vt, Mr, Li, axx, axcs);
    k_pack<<<10240, 256, 0, stream>>>(x, zs, axx, axcs, xgbf);
    k_bapplyM<COU><<<dim3(16, 32), 256, 0, stream>>>(Wbtu, b_u, tt, xgbf, pu);
    k_napplyM_upd<<<1024, 256, 0, stream>>>(se, W_u, b_u, xgbf, pu, rr, state, out);
}

// Round 8
// 229.087 us; speedup vs baseline: 5.5559x; 1.1705x over previous
//
#include <hip/hip_runtime.h>
#include <math.h>

namespace {
constexpr int BB = 32;
constexpr int NN = 1024;
constexpr int ET = 16;
constexpr int HH = 64;
constexpr int CIN = 65;       // Din + HID
constexpr int KI = 2*CIN;     // 130
constexpr int COG = 2*HH;     // 128
constexpr int COU = HH;       // 64
constexpr int PP = 288;
constexpr int FF = 7;
constexpr int FRQ = 12;
constexpr int XK = 160;       // padded K for MFMA (5 x 32)

typedef __attribute__((ext_vector_type(4))) float f32x4;
typedef __attribute__((ext_vector_type(8))) short s16x8;
typedef unsigned long long ull;

__device__ __forceinline__ float bf2f(unsigned short u) {
    unsigned v = ((unsigned)u) << 16;
    return __builtin_bit_cast(float, v);
}
__device__ __forceinline__ unsigned short f2bf(float f) {
    unsigned u = __builtin_bit_cast(unsigned, f);
    u += 0x7fffu + ((u >> 16) & 1u);   // RNE
    return (unsigned short)(u >> 16);
}
__device__ __forceinline__ float ldany(const float* p) { return *p; }
__device__ __forceinline__ float ldany(const unsigned short* p) { return bf2f(*p); }

// ---------------- prep kernels ----------------
__global__ void k_prep1(const float* __restrict__ SE, const float* __restrict__ Wse,
                        const float* __restrict__ bse, const float* __restrict__ Ttod,
                        const float* __restrict__ Tdow, const int* __restrict__ tidx,
                        float* __restrict__ se, float* __restrict__ tt) {
    int idx = blockIdx.x*blockDim.x + threadIdx.x;
    if (idx < NN*ET) {
        int n = idx / ET, d = idx % ET;
        float acc = bse[d];
        #pragma unroll
        for (int e = 0; e < ET; ++e) acc += SE[n*ET + e]*Wse[e*ET + d];
        se[idx] = acc;
    } else if (idx < NN*ET + BB*ET) {
        int r = idx - NN*ET;
        int b = r / ET, d = r % ET;
        int t = tidx[b]*FRQ;
        tt[r] = Ttod[(t % PP)*ET + d] + Tdow[((t/PP) % FF)*ET + d];
    }
}

__global__ void k_prep2bf(const float* __restrict__ se, const float* __restrict__ tt,
                          unsigned short* __restrict__ stebf) {
    int idx = blockIdx.x*blockDim.x + threadIdx.x;
    if (idx >= BB*NN*ET) return;
    int d = idx % ET;
    int n = (idx/ET) % NN;
    int b = idx/(ET*NN);
    stebf[idx] = f2bf(se[n*ET+d] + tt[b*ET+d]);
}

// Wpool -> bf16 transposed: Wpt[d][o][160] (ki padded 130->160 with zeros)
__global__ void k_prepWpt(const float* __restrict__ Wg, const float* __restrict__ Wu,
                          unsigned short* __restrict__ Wptg, unsigned short* __restrict__ Wptu) {
    int idx = blockIdx.x*blockDim.x + threadIdx.x;
    constexpr int NG2 = ET*COG*XK;
    constexpr int NU2 = ET*COU*XK;
    if (idx < NG2) {
        int d = idx/(COG*XK), r = idx%(COG*XK), o = r/XK, ki = r%XK;
        float v = (ki < KI) ? Wg[((size_t)d*KI + ki)*COG + o] : 0.f;
        Wptg[((size_t)d*COG + o)*XK + ki] = f2bf(v);
    } else if (idx < NG2 + NU2) {
        int j = idx - NG2;
        int d = j/(COU*XK), r = j%(COU*XK), o = r/XK, ki = r%XK;
        float v = (ki < KI) ? Wu[((size_t)d*KI + ki)*COU + o] : 0.f;
        Wptu[((size_t)d*COU + o)*XK + ki] = f2bf(v);
    }
}

// pack xg columns ki 0..64 (+ zero pad 130..159); ki 65..129 are written by k_attn
template<typename T>
__global__ void k_pack(const float* __restrict__ x, const T* __restrict__ sv,
                       unsigned short* __restrict__ xgbf) {
    int idx = blockIdx.x*blockDim.x + threadIdx.x;
    if (idx >= BB*NN*(XK/2)) return;
    int row = idx/(XK/2), c = idx%(XK/2);
    if (c < 32) {
        int k0 = 2*c;
        float v0 = (k0 == 0) ? x[row] : ldany(sv + (size_t)row*HH + k0 - 1);
        float v1 = ldany(sv + (size_t)row*HH + k0);       // ki = k0+1 -> sv[k0]
        ((unsigned*)xgbf)[(size_t)row*(XK/2) + c] = ((unsigned)f2bf(v1) << 16) | f2bf(v0);
    } else if (c == 32) {
        xgbf[(size_t)row*XK + 64] = f2bf(ldany(sv + (size_t)row*HH + 63));
    } else if (c >= 65) {
        ((unsigned*)xgbf)[(size_t)row*(XK/2) + c] = 0;
    }
    // c in [33,64]: ki 66..129 -> written by k_attn, skip
}

// V [b][n][64] (f32 or bf16) -> vt bf16 [b][mb][och][8]  (mb = n/8)
template<typename T>
__global__ void k_cvtVt(const T* __restrict__ V, unsigned short* __restrict__ vt) {
    int idx = blockIdx.x*blockDim.x + threadIdx.x;
    if (idx >= BB*128*64) return;
    int och = idx & 63, mb = (idx >> 6) & 127, b = idx >> 13;
    const T* src = V + ((size_t)b*NN + mb*8)*HH + och;
    float v0=ldany(src), v1=ldany(src+HH), v2=ldany(src+2*HH), v3=ldany(src+3*HH);
    float v4=ldany(src+4*HH), v5=ldany(src+5*HH), v6=ldany(src+6*HH), v7=ldany(src+7*HH);
    ull lo = (ull)f2bf(v0) | ((ull)f2bf(v1)<<16) | ((ull)f2bf(v2)<<32) | ((ull)f2bf(v3)<<48);
    ull hi = (ull)f2bf(v4) | ((ull)f2bf(v5)<<16) | ((ull)f2bf(v6)<<32) | ((ull)f2bf(v7)<<48);
    ull* dst = (ull*)(vt + (size_t)idx*8);
    dst[0] = lo; dst[1] = hi;
}

// ---------------- fused attention pass ----------------
constexpr int SSTR   = 1048;       // 524 dwords = 12 mod 32 -> 4-way max banks
constexpr int S_OFF  = 0;          // 16*1048*2 = 33536
constexpr int XV_OFF = 33536;      // 4096
constexpr int MSH_OFF  = 37632;    // 256
constexpr int MSHC_OFF = 37888;    // 64
constexpr int LP_OFF   = 37952;    // 256
constexpr int AXP_OFF  = 38208;    // 256
constexpr int LSH_OFF  = 38464;    // 64
constexpr int SMEM_BYTES = 38528;  // 4 blocks/CU

template<int PASS>
__global__ __launch_bounds__(256, 4) void k_attn(
    const unsigned short* __restrict__ stebf, const float* __restrict__ Rg,
    const float* __restrict__ SCg, const float* __restrict__ xg,
    const unsigned short* __restrict__ vt,
    float* __restrict__ Mr, float* __restrict__ Li,
    unsigned short* __restrict__ xgout)
{
    extern __shared__ char smem[];
    const int t = threadIdx.x, lane = t & 63, w = t >> 6;
    const int c15 = lane & 15, g = lane >> 4;
    const int strip = blockIdx.x, b = blockIdx.y;
    const size_t bN = (size_t)b * NN;
    const int r0 = strip * 16;

    float* Mshf  = (float*)(smem + MSH_OFF);
    float* MshCf = (float*)(smem + MSHC_OFF);
    float* Lpf   = (float*)(smem + LP_OFF);
    float* Axpf  = (float*)(smem + AXP_OFF);
    float* Lshf  = (float*)(smem + LSH_OFF);

    if (PASS == 1) {
        ((float4*)(smem + XV_OFF))[t] = ((const float4*)(xg + bN))[t];
    }

    {   // phase a: scores via MFMA
        s16x8 af = {0,0,0,0,0,0,0,0};
        if (g < 2) af = *(const s16x8*)(stebf + (bN + r0 + c15)*ET + g*8);
        const float* Rb  = Rg  + (bN + r0 + g*4)*NN;
        const float* SCb = SCg + (size_t)(r0 + g*4)*NN;
        float mx0 = -INFINITY, mx1 = -INFINITY, mx2 = -INFINITY, mx3 = -INFINITY;
        float rc[4], scv[4];
        {
            int col = w*16 + c15;
            #pragma unroll
            for (int q = 0; q < 4; ++q) { rc[q] = Rb[(size_t)q*NN + col]; scv[q] = SCb[(size_t)q*NN + col]; }
        }
        for (int j = 0; j < 16; ++j) {
            int colB = j*64 + w*16 + c15;
            s16x8 bf = {0,0,0,0,0,0,0,0};
            if (g < 2) bf = *(const s16x8*)(stebf + (bN + colB)*ET + g*8);
            float rn[4] = {0.f,0.f,0.f,0.f}, sn[4] = {0.f,0.f,0.f,0.f};
            if (j < 15) {
                int col = colB + 64;
                #pragma unroll
                for (int q = 0; q < 4; ++q) { rn[q] = Rb[(size_t)q*NN + col]; sn[q] = SCb[(size_t)q*NN + col]; }
            }
            f32x4 zero = {0.f,0.f,0.f,0.f};
            f32x4 d = __builtin_amdgcn_mfma_f32_16x16x32_bf16(af, bf, zero, 0, 0, 0);
            #pragma unroll
            for (int q = 0; q < 4; ++q) {
                float s = fmaxf(d[q], 0.f) + rc[q] + scv[q];
                if (PASS == 1) {
                    if (q == 0) mx0 = fmaxf(mx0, s);
                    if (q == 1) mx1 = fmaxf(mx1, s);
                    if (q == 2) mx2 = fmaxf(mx2, s);
                    if (q == 3) mx3 = fmaxf(mx3, s);
                }
                int rowl = g*4 + q;
                *(unsigned short*)(smem + S_OFF + (unsigned)(rowl*SSTR + colB)*2u) = f2bf(s);
            }
            #pragma unroll
            for (int q = 0; q < 4; ++q) { rc[q] = rn[q]; scv[q] = sn[q]; }
        }
        if (PASS == 1) {
            float mxa[4] = {mx0, mx1, mx2, mx3};
            #pragma unroll
            for (int q = 0; q < 4; ++q) {
                float m = mxa[q];
                m = fmaxf(m, __shfl_xor(m, 1));
                m = fmaxf(m, __shfl_xor(m, 2));
                m = fmaxf(m, __shfl_xor(m, 4));
                m = fmaxf(m, __shfl_xor(m, 8));
                if (c15 == 0) Mshf[w*16 + g*4 + q] = m;
            }
        }
    }
    __syncthreads();

    if (PASS == 1) {
        if (t < 16) {
            float m = fmaxf(fmaxf(Mshf[t], Mshf[16+t]), fmaxf(Mshf[32+t], Mshf[48+t]));
            MshCf[t] = m;
            Mr[bN + r0 + t] = m;
        }
    } else {
        if (t < 16) MshCf[t] = Mr[bN + r0 + t];
        if (t >= 64 && t < 80) Lshf[t-64] = Li[bN + r0 + (t-64)];
    }
    __syncthreads();

    {   // phase b: exp in place (+ L, axx on PASS1)
        const int rowl = c15;
        const float m = MshCf[rowl];
        float L = 0.f, ax = 0.f;
        for (int it = 0; it < 16; ++it) {
            int k = w*256 + it*16 + g*4;
            unsigned byteo = (unsigned)(rowl*SSTR + k)*2u;
            ull v = *(ull*)(smem + S_OFF + byteo);
            float s0 = bf2f((unsigned short)v);
            float s1 = bf2f((unsigned short)(v >> 16));
            float s2 = bf2f((unsigned short)(v >> 32));
            float s3 = bf2f((unsigned short)(v >> 48));
            float p0 = __expf(s0 - m), p1 = __expf(s1 - m);
            float p2 = __expf(s2 - m), p3 = __expf(s3 - m);
            if (PASS == 1) {
                float4 xq = *(const float4*)(smem + XV_OFF + k*4);
                L += (p0 + p1) + (p2 + p3);
                ax += p0*xq.x + p1*xq.y + p2*xq.z + p3*xq.w;
            }
            unsigned lo = ((unsigned)f2bf(p1) << 16) | f2bf(p0);
            unsigned hi = ((unsigned)f2bf(p3) << 16) | f2bf(p2);
            *(ull*)(smem + S_OFF + byteo) = ((ull)hi << 32) | lo;
        }
        if (PASS == 1) {
            L += __shfl_xor(L, 16); L += __shfl_xor(L, 32);
            ax += __shfl_xor(ax, 16); ax += __shfl_xor(ax, 32);
            if (g == 0) { Lpf[w*16 + rowl] = L; Axpf[w*16 + rowl] = ax; }
        }
    }
    __syncthreads();
    if (PASS == 1) {
        if (t < 16) {
            float Lt = Lpf[t] + Lpf[16+t] + Lpf[32+t] + Lpf[48+t];
            float li = 1.f / Lt;
            Lshf[t] = li;
            Li[bN + r0 + t] = li;
            // axx -> xgbf column 65 (bf16)
            xgout[(bN + r0 + t)*XK + 65] =
                f2bf((Axpf[t] + Axpf[16+t] + Axpf[32+t] + Axpf[48+t]) * li);
        }
        __syncthreads();
    }

    {   // phase c: PV via MFMA; A from LDS, B from global vt; out -> xgbf cols 66..129
        f32x4 acc = {0.f,0.f,0.f,0.f};
        const unsigned short* vtb = vt + ((size_t)b*128*64 + (w*16 + c15))*8;
        #pragma unroll 4
        for (int j = 0; j < 16; ++j) {
            #pragma unroll
            for (int ks = 0; ks < 2; ++ks) {
                s16x8 a  = *(const s16x8*)(smem + S_OFF + (unsigned)(c15*SSTR + j*64 + ks*32 + g*8)*2u);
                s16x8 bv = *(const s16x8*)(vtb + (size_t)(j*8 + ks*4 + g)*512);
                acc = __builtin_amdgcn_mfma_f32_16x16x32_bf16(a, bv, acc, 0, 0, 0);
            }
        }
        #pragma unroll
        for (int q = 0; q < 4; ++q) {
            int rowl = g*4 + q;
            float li = Lshf[rowl];
            xgout[(bN + r0 + rowl)*XK + 66 + w*16 + c15] = f2bf(acc[q] * li);
        }
    }
}

// ---------------- fused avwgcn-apply: all-d MFMA + ste-weighted reduce + epilogue ----------------
// out[b,n,o] = sum_d ste[b,n,d] * (xg[b,n,:]@Wpool[d,:,o] + bpool[d,o])
template<int COUT, int EPI>   // EPI 0: gate (sigmoid -> zs,r), 1: upd (tanh -> out)
__global__ __launch_bounds__(256, 2) void k_apply(
    const unsigned short* __restrict__ Wpt, const float* __restrict__ bias,
    const unsigned short* __restrict__ stebf, const unsigned short* __restrict__ xgbf,
    const float* __restrict__ state, unsigned short* __restrict__ zsbf,
    unsigned short* __restrict__ rrbf, float* __restrict__ out)
{
    const int t = threadIdx.x, lane = t & 63, w = t >> 6;
    const int c15 = lane & 15, g = lane >> 4;
    const int n0 = blockIdx.x*32, b = blockIdx.y, oh = blockIdx.z;
    const int o = oh*64 + w*16 + c15;

    f32x4 acc[16][2];
    #pragma unroll
    for (int d = 0; d < 16; ++d) {
        acc[d][0] = (f32x4){0.f,0.f,0.f,0.f};
        acc[d][1] = (f32x4){0.f,0.f,0.f,0.f};
    }

    const unsigned short* Ar0 = xgbf + ((size_t)b*NN + n0 + c15)*XK + g*8;
    const unsigned short* Ar1 = Ar0 + (size_t)16*XK;
    const unsigned short* Bp  = Wpt + (size_t)o*XK + g*8;

    for (int ks = 0; ks < 5; ++ks) {
        s16x8 a0 = *(const s16x8*)(Ar0 + ks*32);
        s16x8 a1 = *(const s16x8*)(Ar1 + ks*32);
        #pragma unroll
        for (int d = 0; d < 16; ++d) {
            s16x8 bf = *(const s16x8*)(Bp + (size_t)d*COUT*XK + ks*32);
            acc[d][0] = __builtin_amdgcn_mfma_f32_16x16x32_bf16(a0, bf, acc[d][0], 0, 0, 0);
            acc[d][1] = __builtin_amdgcn_mfma_f32_16x16x32_bf16(a1, bf, acc[d][1], 0, 0, 0);
        }
    }

    float biasv[16];
    #pragma unroll
    for (int d = 0; d < 16; ++d) biasv[d] = bias[d*COUT + o];

    #pragma unroll
    for (int mt = 0; mt < 2; ++mt) {
        #pragma unroll
        for (int q = 0; q < 4; ++q) {
            int n = n0 + mt*16 + g*4 + q;
            size_t bn = (size_t)b*NN + n;
            const ull* sp = (const ull*)(stebf + bn*ET);
            float val = 0.f;
            #pragma unroll
            for (int dd = 0; dd < 4; ++dd) {
                ull sv4 = sp[dd];
                float s0 = bf2f((unsigned short)sv4);
                float s1 = bf2f((unsigned short)(sv4 >> 16));
                float s2 = bf2f((unsigned short)(sv4 >> 32));
                float s3 = bf2f((unsigned short)(sv4 >> 48));
                val += s0*(acc[dd*4+0][mt][q] + biasv[dd*4+0]);
                val += s1*(acc[dd*4+1][mt][q] + biasv[dd*4+1]);
                val += s2*(acc[dd*4+2][mt][q] + biasv[dd*4+2]);
                val += s3*(acc[dd*4+3][mt][q] + biasv[dd*4+3]);
            }
            if (EPI == 0) {
                float gv = 1.f/(1.f + __expf(-val));
                if (oh == 0) zsbf[bn*HH + o] = f2bf(gv * state[bn*HH + o]);
                else         rrbf[bn*HH + (o - 64)] = f2bf(gv);
            } else {
                float hc = tanhf(val);
                float rv = bf2f(rrbf[bn*HH + o]);
                out[bn*HH + o] = rv*state[bn*HH + o] + (1.f - rv)*hc;
            }
        }
    }
}

} // namespace

extern "C" void kernel_launch(void* const* d_in, const int* in_sizes, int n_in,
                              void* d_out, int out_size, void* d_ws, size_t ws_size,
                              hipStream_t stream) {
    const float* x     = (const float*)d_in[0];
    const float* R     = (const float*)d_in[1];
    const float* state = (const float*)d_in[2];
    const float* SC    = (const float*)d_in[3];
    const float* SE    = (const float*)d_in[4];
    const float* W_se  = (const float*)d_in[5];
    const float* b_se  = (const float*)d_in[6];
    const float* T_tod = (const float*)d_in[7];
    const float* T_dow = (const float*)d_in[8];
    const float* W_g   = (const float*)d_in[9];
    const float* b_g   = (const float*)d_in[10];
    const float* W_u   = (const float*)d_in[11];
    const float* b_u   = (const float*)d_in[12];
    const int*   tidx  = (const int*)d_in[13];
    float* out = (float*)d_out;
    float* ws = (float*)d_ws;

    // ~25 MB total
    float* se = ws;                                       // 16384 f
    float* tt = se + 16384;                               // 512 f
    float* Mr = tt + 512;                                 // 32768 f
    float* Li = Mr + 32768;                               // 32768 f
    unsigned short* stebf = (unsigned short*)(Li + 32768);// 524288 us
    unsigned short* xgbf  = stebf + 524288;               // 5242880 us
    unsigned short* zsbf  = xgbf + 5242880;               // 2097152 us
    unsigned short* rrbf  = zsbf + 2097152;               // 2097152 us
    unsigned short* vt    = rrbf + 2097152;               // 2097152 us
    unsigned short* Wptg  = vt + 2097152;                 // 327680 us
    unsigned short* Wptu  = Wptg + 327680;                // 163840 us

    k_prep1<<<66, 256, 0, stream>>>(SE, W_se, b_se, T_tod, T_dow, tidx, se, tt);
    k_prep2bf<<<2048, 256, 0, stream>>>(se, tt, stebf);
    k_prepWpt<<<1920, 256, 0, stream>>>(W_g, W_u, Wptg, Wptu);

    k_cvtVt<float><<<1024, 256, 0, stream>>>(state, vt);
    k_attn<1><<<dim3(64, 32), 256, SMEM_BYTES, stream>>>(
        stebf, R, SC, x, vt, Mr, Li, xgbf);
    k_pack<float><<<10240, 256, 0, stream>>>(x, state, xgbf);
    k_apply<COG, 0><<<dim3(32, 32, 2), 256, 0, stream>>>(
        Wptg, b_g, stebf, xgbf, state, zsbf, rrbf, nullptr);

    k_cvtVt<unsigned short><<<1024, 256, 0, stream>>>(zsbf, vt);
    k_attn<2><<<dim3(64, 32), 256, SMEM_BYTES, stream>>>(
        stebf, R, SC, x, vt, Mr, Li, xgbf);
    k_pack<unsigned short><<<10240, 256, 0, stream>>>(x, zsbf, xgbf);
    k_apply<COU, 1><<<dim3(32, 32, 1), 256, 0, stream>>>(
        Wptu, b_u, stebf, xgbf, state, zsbf, rrbf, out);
}